// Round 1
// baseline (2542.397 us; speedup 1.0000x reference)
//
#include <hip/hip_runtime.h>
#include <math.h>

// ---------------------------------------------------------------------------
// GCN 2-layer forward on MI355X. Round 0: correctness-first structure.
//   deg -> dinv -> h1 = x@W1 -> agg1 = A_norm h1 (atomics) -> +b1, relu
//   -> h2 = agg1@W2 -> agg2 = A_norm h2 (atomics, into d_out) -> +b2, log_softmax
// ---------------------------------------------------------------------------

__global__ __launch_bounds__(256) void deg_count_kernel(
    const int* __restrict__ dst, int E, float* __restrict__ deg) {
    int e = blockIdx.x * blockDim.x + threadIdx.x;
    if (e < E) atomicAdd(&deg[dst[e]], 1.0f);
}

__global__ __launch_bounds__(256) void dinv_kernel(float* __restrict__ deg, int N) {
    int n = blockIdx.x * blockDim.x + threadIdx.x;
    if (n < N) deg[n] = rsqrtf(deg[n] + 1.0f);  // +1 for self-loop
}

// C[M,N] = A[M,K] @ B[K,N], fp32. 64x64 tile, BK=16, 256 threads, 4x4 microtile.
__global__ __launch_bounds__(256) void sgemm_kernel(
    const float* __restrict__ A, const float* __restrict__ B,
    float* __restrict__ C, int M, int N, int K) {
    __shared__ float As[16][68];  // transposed: As[k][m], padded (+4) vs bank conflicts
    __shared__ float Bs[16][68];  // Bs[k][n], padded

    const int tid = threadIdx.x;
    const int tx = tid & 15;
    const int ty = tid >> 4;
    const int m0 = blockIdx.x * 64;
    const int n0 = blockIdx.y * 64;

    float acc[4][4] = {};

    for (int k0 = 0; k0 < K; k0 += 16) {
        // A tile: 64 rows x 16 k. Each thread: one float4 (row = tid>>2, k = (tid&3)*4)
        {
            int row = tid >> 2;
            int kk  = (tid & 3) << 2;
            int gr  = m0 + row;
            float4 a = make_float4(0.f, 0.f, 0.f, 0.f);
            if (gr < M) a = *(const float4*)&A[(size_t)gr * K + k0 + kk];
            As[kk + 0][row] = a.x;
            As[kk + 1][row] = a.y;
            As[kk + 2][row] = a.z;
            As[kk + 3][row] = a.w;
        }
        // B tile: 16 k x 64 n. Each thread: one float4 (k = tid>>4, n = (tid&15)*4)
        {
            int kk = tid >> 4;
            int nn = (tid & 15) << 2;
            float4 b = *(const float4*)&B[(size_t)(k0 + kk) * N + n0 + nn];
            *(float4*)&Bs[kk][nn] = b;
        }
        __syncthreads();

#pragma unroll
        for (int k = 0; k < 16; ++k) {
            float4 a = *(float4*)&As[k][ty << 2];
            float4 b = *(float4*)&Bs[k][tx << 2];
            acc[0][0] += a.x * b.x; acc[0][1] += a.x * b.y; acc[0][2] += a.x * b.z; acc[0][3] += a.x * b.w;
            acc[1][0] += a.y * b.x; acc[1][1] += a.y * b.y; acc[1][2] += a.y * b.z; acc[1][3] += a.y * b.w;
            acc[2][0] += a.z * b.x; acc[2][1] += a.z * b.y; acc[2][2] += a.z * b.z; acc[2][3] += a.z * b.w;
            acc[3][0] += a.w * b.x; acc[3][1] += a.w * b.y; acc[3][2] += a.w * b.z; acc[3][3] += a.w * b.w;
        }
        __syncthreads();
    }

#pragma unroll
    for (int i = 0; i < 4; ++i) {
        int gr = m0 + (ty << 2) + i;
        if (gr < M) {
            float4 v = make_float4(acc[i][0], acc[i][1], acc[i][2], acc[i][3]);
            *(float4*)&C[(size_t)gr * N + n0 + (tx << 2)] = v;
        }
    }
}

// Aggregation, F=256: one block per (edge or self-loop), thread = feature.
__global__ __launch_bounds__(256) void agg256_kernel(
    const float* __restrict__ h, const int* __restrict__ ei,
    const float* __restrict__ dinv, float* __restrict__ out, int E, int N) {
    int i = blockIdx.x;
    int s, d;
    float w;
    if (i < E) {
        s = ei[i];
        d = ei[E + i];
        w = dinv[s] * dinv[d];
    } else {
        s = d = i - E;
        float v = dinv[s];
        w = v * v;
    }
    int f = threadIdx.x;
    float val = h[(size_t)s * 256 + f] * w;
    atomicAdd(&out[(size_t)d * 256 + f], val);
}

// Aggregation, F=64: 4 edges per 256-thread block (wave per edge).
__global__ __launch_bounds__(256) void agg64_kernel(
    const float* __restrict__ h, const int* __restrict__ ei,
    const float* __restrict__ dinv, float* __restrict__ out, int E, int N) {
    int i = blockIdx.x * 4 + (threadIdx.x >> 6);
    if (i >= E + N) return;
    int s, d;
    float w;
    if (i < E) {
        s = ei[i];
        d = ei[E + i];
        w = dinv[s] * dinv[d];
    } else {
        s = d = i - E;
        float v = dinv[s];
        w = v * v;
    }
    int f = threadIdx.x & 63;
    float val = h[(size_t)s * 64 + f] * w;
    atomicAdd(&out[(size_t)d * 64 + f], val);
}

// x[i] = relu(x[i] + b[i % 256]) over N*256 elements.
__global__ __launch_bounds__(256) void bias_relu_kernel(
    float* __restrict__ x, const float* __restrict__ b, long total) {
    long i = (long)blockIdx.x * blockDim.x + threadIdx.x;
    if (i < total) x[i] = fmaxf(x[i] + b[i & 255], 0.0f);
}

// In-place over d_out [N,64]: row-wave log_softmax(x + b2).
__global__ __launch_bounds__(256) void logsoftmax_kernel(
    float* __restrict__ io, const float* __restrict__ b2, int N) {
    int row = blockIdx.x * 4 + (threadIdx.x >> 6);
    if (row >= N) return;
    int lane = threadIdx.x & 63;
    float v = io[(size_t)row * 64 + lane] + b2[lane];
    float m = v;
#pragma unroll
    for (int off = 32; off > 0; off >>= 1) m = fmaxf(m, __shfl_xor(m, off, 64));
    float e = expf(v - m);
    float s = e;
#pragma unroll
    for (int off = 32; off > 0; off >>= 1) s += __shfl_xor(s, off, 64);
    io[(size_t)row * 64 + lane] = v - m - logf(s);
}

extern "C" void kernel_launch(void* const* d_in, const int* in_sizes, int n_in,
                              void* d_out, int out_size, void* d_ws, size_t ws_size,
                              hipStream_t stream) {
    const float* x  = (const float*)d_in[0];
    const int*   ei = (const int*)d_in[1];
    const float* W1 = (const float*)d_in[2];
    const float* b1 = (const float*)d_in[3];
    const float* W2 = (const float*)d_in[4];
    const float* b2 = (const float*)d_in[5];
    float* out = (float*)d_out;

    const int N = in_sizes[0] / 256;  // 100000
    const int E = in_sizes[1] / 2;    // 1600000

    // Workspace layout (floats): dinv [128K slot] | h1 [N*256] | agg1 [N*256]
    // h2 aliases h1 (h1 is dead once agg1 is built).
    float* dinv = (float*)d_ws;
    float* h1   = dinv + (1 << 17);
    float* agg1 = h1 + (size_t)N * 256;
    float* h2   = h1;

    hipMemsetAsync(dinv, 0, (size_t)N * sizeof(float), stream);
    hipMemsetAsync(agg1, 0, (size_t)N * 256 * sizeof(float), stream);
    hipMemsetAsync(out, 0, (size_t)N * 64 * sizeof(float), stream);

    // Degrees (in-degree + self-loop) -> dinv = rsqrt(deg)
    deg_count_kernel<<<(E + 255) / 256, 256, 0, stream>>>(ei + E, E, dinv);
    dinv_kernel<<<(N + 255) / 256, 256, 0, stream>>>(dinv, N);

    // h1 = x @ W1
    {
        dim3 grid((N + 63) / 64, 256 / 64);
        sgemm_kernel<<<grid, 256, 0, stream>>>(x, W1, h1, N, 256, 256);
    }

    // agg1 = A_norm @ h1
    agg256_kernel<<<E + N, 256, 0, stream>>>(h1, ei, dinv, agg1, E, N);

    // agg1 = relu(agg1 + b1)
    bias_relu_kernel<<<(int)(((long)N * 256 + 255) / 256), 256, 0, stream>>>(
        agg1, b1, (long)N * 256);

    // h2 = agg1 @ W2
    {
        dim3 grid((N + 63) / 64, 1);
        sgemm_kernel<<<grid, 256, 0, stream>>>(agg1, W2, h2, N, 64, 256);
    }

    // d_out = A_norm @ h2
    agg64_kernel<<<(E + N + 3) / 4, 256, 0, stream>>>(h2, ei, dinv, out, E, N);

    // d_out = log_softmax(d_out + b2)
    logsoftmax_kernel<<<(N + 3) / 4, 256, 0, stream>>>(out, b2, N);
}

// Round 2
// 1085.582 us; speedup vs baseline: 2.3420x; 2.3420x over previous
//
#include <hip/hip_runtime.h>
#include <math.h>

// ---------------------------------------------------------------------------
// GCN 2-layer forward on MI355X. Round 2: CSR aggregation (no fp atomics).
//   cnt -> row_ptr (scan) -> scatter(csr_src, csr_w)
//   h1 = x@W1 ; agg1 = relu(A h1 + b1)  [CSR, fused]
//   h2 = agg1@W2 ; out = log_softmax(A h2 + b2)  [CSR, fused]
// ---------------------------------------------------------------------------

__global__ __launch_bounds__(256) void deg_count_kernel(
    const int* __restrict__ dst, int E, int* __restrict__ cnt) {
    int e = blockIdx.x * blockDim.x + threadIdx.x;
    if (e < E) atomicAdd(&cnt[dst[e]], 1);
}

__global__ __launch_bounds__(256) void dinv_kernel(
    const int* __restrict__ cnt, float* __restrict__ dinv, int N) {
    int n = blockIdx.x * blockDim.x + threadIdx.x;
    if (n < N) dinv[n] = rsqrtf((float)cnt[n] + 1.0f);  // +1 self-loop
}

// Single-block exclusive scan of cnt[N] -> row_ptr[N+1]. 1024 threads.
__global__ __launch_bounds__(1024) void scan_kernel(
    const int* __restrict__ cnt, int* __restrict__ row_ptr, int N) {
    __shared__ int sdata[1024];
    const int tid = threadIdx.x;
    const int chunk = (N + 1023) / 1024;
    const int start = tid * chunk;
    const int end = min(start + chunk, N);
    int sum = 0;
    for (int i = start; i < end; ++i) sum += cnt[i];
    sdata[tid] = sum;
    __syncthreads();
    // Hillis-Steele inclusive scan over 1024 partials
    for (int off = 1; off < 1024; off <<= 1) {
        int v = (tid >= off) ? sdata[tid - off] : 0;
        __syncthreads();
        if (tid >= off) sdata[tid] += v;
        __syncthreads();
    }
    int run = (tid == 0) ? 0 : sdata[tid - 1];
    for (int i = start; i < end; ++i) {
        row_ptr[i] = run;
        run += cnt[i];
    }
    if (tid == 1023) row_ptr[N] = sdata[1023];
}

__global__ __launch_bounds__(256) void scatter_kernel(
    const int* __restrict__ src, const int* __restrict__ dst,
    const float* __restrict__ dinv, const int* __restrict__ row_ptr,
    int* __restrict__ cursor, int* __restrict__ csr_src,
    float* __restrict__ csr_w, int E) {
    int e = blockIdx.x * blockDim.x + threadIdx.x;
    if (e >= E) return;
    int s = src[e], d = dst[e];
    int pos = row_ptr[d] + atomicAdd(&cursor[d], 1);
    csr_src[pos] = s;
    csr_w[pos] = dinv[s] * dinv[d];
}

// C[M,N] = A[M,K] @ B[K,N], fp32. 64x64 tile, BK=16, 256 threads, 4x4 microtile.
__global__ __launch_bounds__(256) void sgemm_kernel(
    const float* __restrict__ A, const float* __restrict__ B,
    float* __restrict__ C, int M, int N, int K) {
    __shared__ float As[16][68];
    __shared__ float Bs[16][68];

    const int tid = threadIdx.x;
    const int tx = tid & 15;
    const int ty = tid >> 4;
    const int m0 = blockIdx.x * 64;
    const int n0 = blockIdx.y * 64;

    float acc[4][4] = {};

    for (int k0 = 0; k0 < K; k0 += 16) {
        {
            int row = tid >> 2;
            int kk  = (tid & 3) << 2;
            int gr  = m0 + row;
            float4 a = make_float4(0.f, 0.f, 0.f, 0.f);
            if (gr < M) a = *(const float4*)&A[(size_t)gr * K + k0 + kk];
            As[kk + 0][row] = a.x;
            As[kk + 1][row] = a.y;
            As[kk + 2][row] = a.z;
            As[kk + 3][row] = a.w;
        }
        {
            int kk = tid >> 4;
            int nn = (tid & 15) << 2;
            float4 b = *(const float4*)&B[(size_t)(k0 + kk) * N + n0 + nn];
            *(float4*)&Bs[kk][nn] = b;
        }
        __syncthreads();

#pragma unroll
        for (int k = 0; k < 16; ++k) {
            float4 a = *(float4*)&As[k][ty << 2];
            float4 b = *(float4*)&Bs[k][tx << 2];
            acc[0][0] += a.x * b.x; acc[0][1] += a.x * b.y; acc[0][2] += a.x * b.z; acc[0][3] += a.x * b.w;
            acc[1][0] += a.y * b.x; acc[1][1] += a.y * b.y; acc[1][2] += a.y * b.z; acc[1][3] += a.y * b.w;
            acc[2][0] += a.z * b.x; acc[2][1] += a.z * b.y; acc[2][2] += a.z * b.z; acc[2][3] += a.z * b.w;
            acc[3][0] += a.w * b.x; acc[3][1] += a.w * b.y; acc[3][2] += a.w * b.z; acc[3][3] += a.w * b.w;
        }
        __syncthreads();
    }

#pragma unroll
    for (int i = 0; i < 4; ++i) {
        int gr = m0 + (ty << 2) + i;
        if (gr < M) {
            float4 v = make_float4(acc[i][0], acc[i][1], acc[i][2], acc[i][3]);
            *(float4*)&C[(size_t)gr * N + n0 + (tx << 2)] = v;
        }
    }
}

// CSR aggregation, F=256: one block per dst node; fused +bias, relu.
__global__ __launch_bounds__(256) void agg256_csr_kernel(
    const float* __restrict__ h, const int* __restrict__ csr_src,
    const float* __restrict__ csr_w, const int* __restrict__ row_ptr,
    const float* __restrict__ dinv, const float* __restrict__ bias,
    float* __restrict__ out, int N) {
    const int d = blockIdx.x;
    const int f = threadIdx.x;
    float dv = dinv[d];
    float acc = h[(size_t)d * 256 + f] * dv * dv;  // self-loop
    const int beg = row_ptr[d], end = row_ptr[d + 1];
#pragma unroll 4
    for (int e = beg; e < end; ++e) {
        int s = csr_src[e];
        float w = csr_w[e];
        acc += h[(size_t)s * 256 + f] * w;
    }
    out[(size_t)d * 256 + f] = fmaxf(acc + bias[f], 0.0f);
}

// CSR aggregation, F=64: wave per dst node; fused +bias, log_softmax.
__global__ __launch_bounds__(256) void agg64_csr_kernel(
    const float* __restrict__ h, const int* __restrict__ csr_src,
    const float* __restrict__ csr_w, const int* __restrict__ row_ptr,
    const float* __restrict__ dinv, const float* __restrict__ bias,
    float* __restrict__ out, int N) {
    const int d = blockIdx.x * 4 + (threadIdx.x >> 6);
    if (d >= N) return;
    const int lane = threadIdx.x & 63;
    float dv = dinv[d];
    float acc = h[(size_t)d * 64 + lane] * dv * dv;  // self-loop
    const int beg = row_ptr[d], end = row_ptr[d + 1];
#pragma unroll 4
    for (int e = beg; e < end; ++e) {
        int s = csr_src[e];
        float w = csr_w[e];
        acc += h[(size_t)s * 64 + lane] * w;
    }
    float v = acc + bias[lane];
    float m = v;
#pragma unroll
    for (int off = 32; off > 0; off >>= 1) m = fmaxf(m, __shfl_xor(m, off, 64));
    float ex = expf(v - m);
    float ssum = ex;
#pragma unroll
    for (int off = 32; off > 0; off >>= 1) ssum += __shfl_xor(ssum, off, 64);
    out[(size_t)d * 64 + lane] = v - m - logf(ssum);
}

extern "C" void kernel_launch(void* const* d_in, const int* in_sizes, int n_in,
                              void* d_out, int out_size, void* d_ws, size_t ws_size,
                              hipStream_t stream) {
    const float* x  = (const float*)d_in[0];
    const int*   ei = (const int*)d_in[1];
    const float* W1 = (const float*)d_in[2];
    const float* b1 = (const float*)d_in[3];
    const float* W2 = (const float*)d_in[4];
    const float* b2 = (const float*)d_in[5];
    float* out = (float*)d_out;

    const int N = in_sizes[0] / 256;  // 100000
    const int E = in_sizes[1] / 2;    // 1600000
    const int NP = 102400;            // padded N slot

    // Workspace layout (4-byte units):
    char* ws = (char*)d_ws;
    int*   cnt     = (int*)ws;                      ws += NP * 4;
    int*   cursor  = (int*)ws;                      ws += NP * 4;
    float* dinv    = (float*)ws;                    ws += NP * 4;
    int*   row_ptr = (int*)ws;                      ws += (NP + 4) * 4;
    int*   csr_src = (int*)ws;                      ws += (size_t)E * 4;
    float* csr_w   = (float*)ws;                    ws += (size_t)E * 4;
    float* h1      = (float*)ws;                    ws += (size_t)N * 256 * 4;
    float* agg1    = (float*)ws;                    ws += (size_t)N * 256 * 4;
    float* h2      = h1;  // h1 dead once agg1 built

    hipMemsetAsync(cnt, 0, (size_t)N * sizeof(int), stream);
    hipMemsetAsync(cursor, 0, (size_t)N * sizeof(int), stream);

    // CSR build
    deg_count_kernel<<<(E + 255) / 256, 256, 0, stream>>>(ei + E, E, cnt);
    dinv_kernel<<<(N + 255) / 256, 256, 0, stream>>>(cnt, dinv, N);
    scan_kernel<<<1, 1024, 0, stream>>>(cnt, row_ptr, N);
    scatter_kernel<<<(E + 255) / 256, 256, 0, stream>>>(
        ei, ei + E, dinv, row_ptr, cursor, csr_src, csr_w, E);

    // h1 = x @ W1
    {
        dim3 grid((N + 63) / 64, 256 / 64);
        sgemm_kernel<<<grid, 256, 0, stream>>>(x, W1, h1, N, 256, 256);
    }

    // agg1 = relu(A h1 + b1)
    agg256_csr_kernel<<<N, 256, 0, stream>>>(
        h1, csr_src, csr_w, row_ptr, dinv, b1, agg1, N);

    // h2 = agg1 @ W2
    {
        dim3 grid((N + 63) / 64, 1);
        sgemm_kernel<<<grid, 256, 0, stream>>>(agg1, W2, h2, N, 64, 256);
    }

    // out = log_softmax(A h2 + b2)
    agg64_csr_kernel<<<(N + 3) / 4, 256, 0, stream>>>(
        h2, csr_src, csr_w, row_ptr, dinv, b2, out, N);
}

// Round 3
// 912.809 us; speedup vs baseline: 2.7852x; 1.1893x over previous
//
#include <hip/hip_runtime.h>
#include <math.h>

// ---------------------------------------------------------------------------
// GCN 2-layer forward on MI355X. Round 3: bf16 MFMA GEMMs + bf16 h1 storage.
//   CSR build (unchanged) ; W1,W2 pre-cast+transposed to bf16
//   h1b = bf16(x @ W1)            [MFMA 16x16x32, inline fp32->bf16 staging]
//   agg1 = relu(A h1b + b1)       [CSR gather of bf16 rows, fp32 accum]
//   h2 = agg1 @ W2                [MFMA, fp32 out]
//   out = log_softmax(A h2 + b2)  [CSR, fp32]
// ---------------------------------------------------------------------------

typedef __attribute__((ext_vector_type(8))) short bf16x8;
typedef __attribute__((ext_vector_type(4))) float f32x4;

__device__ inline unsigned short f2bf(float f) {
    union { float f; unsigned int u; } v; v.f = f;
    unsigned int r = v.u + 0x7fffu + ((v.u >> 16) & 1u);  // RNE
    return (unsigned short)(r >> 16);
}
__device__ inline float bf2f_lo(unsigned int u) {
    union { unsigned int u; float f; } v; v.u = u << 16; return v.f;
}
__device__ inline float bf2f_hi(unsigned int u) {
    union { unsigned int u; float f; } v; v.u = u & 0xffff0000u; return v.f;
}

// ---------------- CSR build ----------------
__global__ __launch_bounds__(256) void deg_count_kernel(
    const int* __restrict__ dst, int E, int* __restrict__ cnt) {
    int e = blockIdx.x * blockDim.x + threadIdx.x;
    if (e < E) atomicAdd(&cnt[dst[e]], 1);
}

__global__ __launch_bounds__(256) void dinv_kernel(
    const int* __restrict__ cnt, float* __restrict__ dinv, int N) {
    int n = blockIdx.x * blockDim.x + threadIdx.x;
    if (n < N) dinv[n] = rsqrtf((float)cnt[n] + 1.0f);  // +1 self-loop
}

__global__ __launch_bounds__(1024) void scan_kernel(
    const int* __restrict__ cnt, int* __restrict__ row_ptr, int N) {
    __shared__ int sdata[1024];
    const int tid = threadIdx.x;
    const int chunk = (N + 1023) / 1024;
    const int start = tid * chunk;
    const int end = min(start + chunk, N);
    int sum = 0;
    for (int i = start; i < end; ++i) sum += cnt[i];
    sdata[tid] = sum;
    __syncthreads();
    for (int off = 1; off < 1024; off <<= 1) {
        int v = (tid >= off) ? sdata[tid - off] : 0;
        __syncthreads();
        if (tid >= off) sdata[tid] += v;
        __syncthreads();
    }
    int run = (tid == 0) ? 0 : sdata[tid - 1];
    for (int i = start; i < end; ++i) {
        row_ptr[i] = run;
        run += cnt[i];
    }
    if (tid == 1023) row_ptr[N] = sdata[1023];
}

__global__ __launch_bounds__(256) void scatter_kernel(
    const int* __restrict__ src, const int* __restrict__ dst,
    const float* __restrict__ dinv, const int* __restrict__ row_ptr,
    int* __restrict__ cursor, int* __restrict__ csr_src,
    float* __restrict__ csr_w, int E) {
    int e = blockIdx.x * blockDim.x + threadIdx.x;
    if (e >= E) return;
    int s = src[e], d = dst[e];
    int pos = row_ptr[d] + atomicAdd(&cursor[d], 1);
    csr_src[pos] = s;
    csr_w[pos] = dinv[s] * dinv[d];
}

// ---------------- weight cast+transpose: Wt[n][k] = bf16(W[k][n]) ----------
__global__ __launch_bounds__(256) void castw_kernel(
    const float* __restrict__ W, unsigned short* __restrict__ Wt,
    int K, int Ncol) {
    int i = blockIdx.x * 256 + threadIdx.x;
    if (i < K * Ncol) {
        int n = i / K;
        int k = i - n * K;
        Wt[i] = f2bf(W[(size_t)k * Ncol + n]);
    }
}

// ---------------- GEMM1: C[M,256] = bf16(A[M,256] @ W1), MFMA ----------------
// Block 256 thr (4 waves), tile 64(M) x 256(N), BK=32. Wave w owns cols [64w,64w+64).
__global__ __launch_bounds__(256) void gemm1_kernel(
    const float* __restrict__ A, const unsigned short* __restrict__ Bt,
    unsigned short* __restrict__ C, int M) {
    __shared__ unsigned short As[64][32];   // As[m][k]
    __shared__ unsigned short Bs[256][32];  // Bs[n][k] (transposed weight)

    const int tid = threadIdx.x;
    const int wave = tid >> 6, lane = tid & 63;
    const int quad = lane >> 4, l15 = lane & 15;
    const int m0 = blockIdx.x * 64;

    f32x4 acc[4][4] = {};

    const int arow = tid >> 2;
    const int akk = (tid & 3) << 3;
    const int gr = m0 + arow;

    for (int k0 = 0; k0 < 256; k0 += 32) {
        // stage A (fp32 -> bf16): thread loads 8 floats of row `arow`
        float4 a0 = make_float4(0.f, 0.f, 0.f, 0.f), a1 = a0;
        if (gr < M) {
            a0 = *(const float4*)&A[(size_t)gr * 256 + k0 + akk];
            a1 = *(const float4*)&A[(size_t)gr * 256 + k0 + akk + 4];
        }
        bf16x8 av;
        av[0] = (short)f2bf(a0.x); av[1] = (short)f2bf(a0.y);
        av[2] = (short)f2bf(a0.z); av[3] = (short)f2bf(a0.w);
        av[4] = (short)f2bf(a1.x); av[5] = (short)f2bf(a1.y);
        av[6] = (short)f2bf(a1.z); av[7] = (short)f2bf(a1.w);
        *(bf16x8*)&As[arow][akk] = av;

        // stage B: thread loads 32 bf16 of Wt row `tid`
        const unsigned short* bsrc = &Bt[(size_t)tid * 256 + k0];
        *(bf16x8*)&Bs[tid][0]  = *(const bf16x8*)&bsrc[0];
        *(bf16x8*)&Bs[tid][8]  = *(const bf16x8*)&bsrc[8];
        *(bf16x8*)&Bs[tid][16] = *(const bf16x8*)&bsrc[16];
        *(bf16x8*)&Bs[tid][24] = *(const bf16x8*)&bsrc[24];
        __syncthreads();

        bf16x8 af[4], bfv[4];
#pragma unroll
        for (int mt = 0; mt < 4; ++mt)
            af[mt] = *(const bf16x8*)&As[mt * 16 + l15][quad * 8];
#pragma unroll
        for (int nt = 0; nt < 4; ++nt)
            bfv[nt] = *(const bf16x8*)&Bs[wave * 64 + nt * 16 + l15][quad * 8];
#pragma unroll
        for (int mt = 0; mt < 4; ++mt)
#pragma unroll
            for (int nt = 0; nt < 4; ++nt)
                acc[mt][nt] = __builtin_amdgcn_mfma_f32_16x16x32_bf16(
                    af[mt], bfv[nt], acc[mt][nt], 0, 0, 0);
        __syncthreads();
    }

#pragma unroll
    for (int mt = 0; mt < 4; ++mt) {
#pragma unroll
        for (int nt = 0; nt < 4; ++nt) {
            int gcol = wave * 64 + nt * 16 + l15;
#pragma unroll
            for (int r = 0; r < 4; ++r) {
                int grow = m0 + mt * 16 + quad * 4 + r;
                if (grow < M)
                    C[(size_t)grow * 256 + gcol] = f2bf(acc[mt][nt][r]);
            }
        }
    }
}

// ---------------- GEMM2: C[M,64] = agg1[M,256] @ W2, fp32 out, MFMA ---------
// Block 256 thr (4 waves), tile 64(M) x 64(N), BK=32. Wave w owns rows [16w,16w+16).
__global__ __launch_bounds__(256) void gemm2_kernel(
    const float* __restrict__ A, const unsigned short* __restrict__ Bt,
    float* __restrict__ C, int M) {
    __shared__ unsigned short As[64][32];
    __shared__ unsigned short Bs[64][32];

    const int tid = threadIdx.x;
    const int wave = tid >> 6, lane = tid & 63;
    const int quad = lane >> 4, l15 = lane & 15;
    const int m0 = blockIdx.x * 64;

    f32x4 acc[4] = {};

    const int arow = tid >> 2;
    const int akk = (tid & 3) << 3;
    const int gr = m0 + arow;
    const int bn = tid & 63, bkc = (tid >> 6) << 3;

    for (int k0 = 0; k0 < 256; k0 += 32) {
        float4 a0 = make_float4(0.f, 0.f, 0.f, 0.f), a1 = a0;
        if (gr < M) {
            a0 = *(const float4*)&A[(size_t)gr * 256 + k0 + akk];
            a1 = *(const float4*)&A[(size_t)gr * 256 + k0 + akk + 4];
        }
        bf16x8 av;
        av[0] = (short)f2bf(a0.x); av[1] = (short)f2bf(a0.y);
        av[2] = (short)f2bf(a0.z); av[3] = (short)f2bf(a0.w);
        av[4] = (short)f2bf(a1.x); av[5] = (short)f2bf(a1.y);
        av[6] = (short)f2bf(a1.z); av[7] = (short)f2bf(a1.w);
        *(bf16x8*)&As[arow][akk] = av;

        *(bf16x8*)&Bs[bn][bkc] = *(const bf16x8*)&Bt[(size_t)bn * 256 + k0 + bkc];
        __syncthreads();

        bf16x8 af = *(const bf16x8*)&As[wave * 16 + l15][quad * 8];
#pragma unroll
        for (int nt = 0; nt < 4; ++nt) {
            bf16x8 bfv = *(const bf16x8*)&Bs[nt * 16 + l15][quad * 8];
            acc[nt] = __builtin_amdgcn_mfma_f32_16x16x32_bf16(af, bfv, acc[nt], 0, 0, 0);
        }
        __syncthreads();
    }

#pragma unroll
    for (int nt = 0; nt < 4; ++nt) {
#pragma unroll
        for (int r = 0; r < 4; ++r) {
            int grow = m0 + wave * 16 + quad * 4 + r;
            if (grow < M) C[(size_t)grow * 64 + nt * 16 + l15] = acc[nt][r];
        }
    }
}

// ---- CSR aggregation over bf16 h1 rows, F=256: wave per node, 4/block -----
__global__ __launch_bounds__(256) void agg256b_kernel(
    const unsigned int* __restrict__ h1b,  // bf16 pairs, row = 128 uints
    const int* __restrict__ csr_src, const float* __restrict__ csr_w,
    const int* __restrict__ row_ptr, const float* __restrict__ dinv,
    const float* __restrict__ bias, float* __restrict__ out, int N) {
    const int node = blockIdx.x * 4 + (threadIdx.x >> 6);
    if (node >= N) return;
    const int lane = threadIdx.x & 63;
    const uint2* h = (const uint2*)h1b;  // row = 64 uint2

    float dv = dinv[node];
    float w0 = dv * dv;  // self-loop
    uint2 p = h[(size_t)node * 64 + lane];
    float4 acc;
    acc.x = bf2f_lo(p.x) * w0; acc.y = bf2f_hi(p.x) * w0;
    acc.z = bf2f_lo(p.y) * w0; acc.w = bf2f_hi(p.y) * w0;

    const int beg = row_ptr[node], end = row_ptr[node + 1];
    for (int e = beg; e < end; ++e) {
        int s = csr_src[e];
        float w = csr_w[e];
        uint2 q = h[(size_t)s * 64 + lane];
        acc.x += bf2f_lo(q.x) * w; acc.y += bf2f_hi(q.x) * w;
        acc.z += bf2f_lo(q.y) * w; acc.w += bf2f_hi(q.y) * w;
    }
    float4 b = *(const float4*)&bias[lane * 4];
    float4 o;
    o.x = fmaxf(acc.x + b.x, 0.f); o.y = fmaxf(acc.y + b.y, 0.f);
    o.z = fmaxf(acc.z + b.z, 0.f); o.w = fmaxf(acc.w + b.w, 0.f);
    *(float4*)&out[(size_t)node * 256 + lane * 4] = o;
}

// ---- CSR aggregation F=64 (fp32 h2) + bias + log_softmax, wave per node ---
__global__ __launch_bounds__(256) void agg64_csr_kernel(
    const float* __restrict__ h, const int* __restrict__ csr_src,
    const float* __restrict__ csr_w, const int* __restrict__ row_ptr,
    const float* __restrict__ dinv, const float* __restrict__ bias,
    float* __restrict__ out, int N) {
    const int d = blockIdx.x * 4 + (threadIdx.x >> 6);
    if (d >= N) return;
    const int lane = threadIdx.x & 63;
    float dv = dinv[d];
    float acc = h[(size_t)d * 64 + lane] * dv * dv;
    const int beg = row_ptr[d], end = row_ptr[d + 1];
    for (int e = beg; e < end; ++e) {
        int s = csr_src[e];
        float w = csr_w[e];
        acc += h[(size_t)s * 64 + lane] * w;
    }
    float v = acc + bias[lane];
    float m = v;
#pragma unroll
    for (int off = 32; off > 0; off >>= 1) m = fmaxf(m, __shfl_xor(m, off, 64));
    float ex = expf(v - m);
    float ssum = ex;
#pragma unroll
    for (int off = 32; off > 0; off >>= 1) ssum += __shfl_xor(ssum, off, 64);
    out[(size_t)d * 64 + lane] = v - m - logf(ssum);
}

extern "C" void kernel_launch(void* const* d_in, const int* in_sizes, int n_in,
                              void* d_out, int out_size, void* d_ws, size_t ws_size,
                              hipStream_t stream) {
    const float* x  = (const float*)d_in[0];
    const int*   ei = (const int*)d_in[1];
    const float* W1 = (const float*)d_in[2];
    const float* b1 = (const float*)d_in[3];
    const float* W2 = (const float*)d_in[4];
    const float* b2 = (const float*)d_in[5];
    float* out = (float*)d_out;

    const int N = in_sizes[0] / 256;  // 100000
    const int E = in_sizes[1] / 2;    // 1600000
    const int NP = 102400;

    // Workspace layout (bytes; all segments 16B-aligned). Total ~194 MB.
    char* ws = (char*)d_ws;
    int*   cnt     = (int*)ws;            ws += (size_t)NP * 4;
    int*   cursor  = (int*)ws;            ws += (size_t)NP * 4;
    float* dinv    = (float*)ws;          ws += (size_t)NP * 4;
    int*   row_ptr = (int*)ws;            ws += (size_t)(NP + 4) * 4;
    int*   csr_src = (int*)ws;            ws += (size_t)E * 4;
    float* csr_w   = (float*)ws;          ws += (size_t)E * 4;
    unsigned short* W1t = (unsigned short*)ws; ws += (size_t)256 * 256 * 2;
    unsigned short* W2t = (unsigned short*)ws; ws += (size_t)256 * 64 * 2;
    unsigned short* h1b = (unsigned short*)ws; ws += (size_t)N * 256 * 2;
    float* agg1    = (float*)ws;          ws += (size_t)N * 256 * 4;
    float* h2      = (float*)ws;          ws += (size_t)N * 64 * 4;

    hipMemsetAsync(cnt, 0, (size_t)N * sizeof(int), stream);
    hipMemsetAsync(cursor, 0, (size_t)N * sizeof(int), stream);

    // CSR build
    deg_count_kernel<<<(E + 255) / 256, 256, 0, stream>>>(ei + E, E, cnt);
    dinv_kernel<<<(N + 255) / 256, 256, 0, stream>>>(cnt, dinv, N);
    scan_kernel<<<1, 1024, 0, stream>>>(cnt, row_ptr, N);
    scatter_kernel<<<(E + 255) / 256, 256, 0, stream>>>(
        ei, ei + E, dinv, row_ptr, cursor, csr_src, csr_w, E);

    // weight casts
    castw_kernel<<<(256 * 256 + 255) / 256, 256, 0, stream>>>(W1, W1t, 256, 256);
    castw_kernel<<<(256 * 64 + 255) / 256, 256, 0, stream>>>(W2, W2t, 256, 64);

    const int mblocks = (N + 63) / 64;

    // h1b = bf16(x @ W1)
    gemm1_kernel<<<mblocks, 256, 0, stream>>>(x, W1t, h1b, N);

    // agg1 = relu(A h1b + b1)
    agg256b_kernel<<<(N + 3) / 4, 256, 0, stream>>>(
        (const unsigned int*)h1b, csr_src, csr_w, row_ptr, dinv, b1, agg1, N);

    // h2 = agg1 @ W2
    gemm2_kernel<<<mblocks, 256, 0, stream>>>(agg1, W2t, h2, N);

    // out = log_softmax(A h2 + b2)
    agg64_csr_kernel<<<(N + 3) / 4, 256, 0, stream>>>(
        h2, csr_src, csr_w, row_ptr, dinv, b2, out, N);
}

// Round 4
// 817.161 us; speedup vs baseline: 3.1113x; 1.1171x over previous
//
#include <hip/hip_runtime.h>
#include <math.h>

// ---------------------------------------------------------------------------
// GCN 2-layer forward on MI355X. Round 4:
//   - agg1 and h2 stored bf16 (agg1 free: gemm2 casts to bf16 anyway)
//   - CSR edges packed as int2{src, w_bits}; 4x edge unroll for MLP
//   - dinv array dropped (recompute rsqrt(cnt+1)); scan seeds cursor
// ---------------------------------------------------------------------------

typedef __attribute__((ext_vector_type(8))) short bf16x8;
typedef __attribute__((ext_vector_type(4))) float f32x4;

__device__ inline unsigned short f2bf(float f) {
    union { float f; unsigned int u; } v; v.f = f;
    unsigned int r = v.u + 0x7fffu + ((v.u >> 16) & 1u);  // RNE
    return (unsigned short)(r >> 16);
}
__device__ inline float bfu2f(unsigned short u) {
    union { unsigned int u; float f; } v; v.u = ((unsigned int)u) << 16; return v.f;
}
__device__ inline float bf2f_lo(unsigned int u) {
    union { unsigned int u; float f; } v; v.u = u << 16; return v.f;
}
__device__ inline float bf2f_hi(unsigned int u) {
    union { unsigned int u; float f; } v; v.u = u & 0xffff0000u; return v.f;
}

// ---------------- CSR build ----------------
__global__ __launch_bounds__(256) void deg_count_kernel(
    const int* __restrict__ dst, int E, int* __restrict__ cnt) {
    int e = blockIdx.x * blockDim.x + threadIdx.x;
    if (e < E) atomicAdd(&cnt[dst[e]], 1);
}

// Exclusive scan cnt[N] -> row_ptr[N+1]; also seeds cursor = row_ptr[0..N).
__global__ __launch_bounds__(1024) void scan_kernel(
    const int* __restrict__ cnt, int* __restrict__ row_ptr,
    int* __restrict__ cursor, int N) {
    __shared__ int sdata[1024];
    const int tid = threadIdx.x;
    const int chunk = (N + 1023) / 1024;
    const int start = tid * chunk;
    const int end = min(start + chunk, N);
    int sum = 0;
    for (int i = start; i < end; ++i) sum += cnt[i];
    sdata[tid] = sum;
    __syncthreads();
    for (int off = 1; off < 1024; off <<= 1) {
        int v = (tid >= off) ? sdata[tid - off] : 0;
        __syncthreads();
        if (tid >= off) sdata[tid] += v;
        __syncthreads();
    }
    int run = (tid == 0) ? 0 : sdata[tid - 1];
    for (int i = start; i < end; ++i) {
        row_ptr[i] = run;
        cursor[i] = run;
        run += cnt[i];
    }
    if (tid == 1023) row_ptr[N] = sdata[1023];
}

__global__ __launch_bounds__(256) void scatter_kernel(
    const int* __restrict__ src, const int* __restrict__ dst,
    const int* __restrict__ cnt, int* __restrict__ cursor,
    int2* __restrict__ csr_ew, int E) {
    int e = blockIdx.x * blockDim.x + threadIdx.x;
    if (e >= E) return;
    int s = src[e], d = dst[e];
    float w = rsqrtf((float)cnt[s] + 1.0f) * rsqrtf((float)cnt[d] + 1.0f);
    int pos = atomicAdd(&cursor[d], 1);
    int2 rec;
    rec.x = s;
    rec.y = __float_as_int(w);
    csr_ew[pos] = rec;
}

// ---------------- weight cast+transpose: Wt[n][k] = bf16(W[k][n]) ----------
__global__ __launch_bounds__(256) void castw_kernel(
    const float* __restrict__ W, unsigned short* __restrict__ Wt,
    int K, int Ncol) {
    int i = blockIdx.x * 256 + threadIdx.x;
    if (i < K * Ncol) {
        int n = i / K;
        int k = i - n * K;
        Wt[i] = f2bf(W[(size_t)k * Ncol + n]);
    }
}

// ---------------- GEMM1: h1b[M,256] = bf16(x[M,256] @ W1), MFMA -------------
__global__ __launch_bounds__(256) void gemm1_kernel(
    const float* __restrict__ A, const unsigned short* __restrict__ Bt,
    unsigned short* __restrict__ C, int M) {
    __shared__ unsigned short As[64][32];
    __shared__ unsigned short Bs[256][32];

    const int tid = threadIdx.x;
    const int wave = tid >> 6, lane = tid & 63;
    const int quad = lane >> 4, l15 = lane & 15;
    const int m0 = blockIdx.x * 64;

    f32x4 acc[4][4] = {};

    const int arow = tid >> 2;
    const int akk = (tid & 3) << 3;
    const int gr = m0 + arow;

    for (int k0 = 0; k0 < 256; k0 += 32) {
        float4 a0 = make_float4(0.f, 0.f, 0.f, 0.f), a1 = a0;
        if (gr < M) {
            a0 = *(const float4*)&A[(size_t)gr * 256 + k0 + akk];
            a1 = *(const float4*)&A[(size_t)gr * 256 + k0 + akk + 4];
        }
        bf16x8 av;
        av[0] = (short)f2bf(a0.x); av[1] = (short)f2bf(a0.y);
        av[2] = (short)f2bf(a0.z); av[3] = (short)f2bf(a0.w);
        av[4] = (short)f2bf(a1.x); av[5] = (short)f2bf(a1.y);
        av[6] = (short)f2bf(a1.z); av[7] = (short)f2bf(a1.w);
        *(bf16x8*)&As[arow][akk] = av;

        const unsigned short* bsrc = &Bt[(size_t)tid * 256 + k0];
        *(bf16x8*)&Bs[tid][0]  = *(const bf16x8*)&bsrc[0];
        *(bf16x8*)&Bs[tid][8]  = *(const bf16x8*)&bsrc[8];
        *(bf16x8*)&Bs[tid][16] = *(const bf16x8*)&bsrc[16];
        *(bf16x8*)&Bs[tid][24] = *(const bf16x8*)&bsrc[24];
        __syncthreads();

        bf16x8 af[4], bfv[4];
#pragma unroll
        for (int mt = 0; mt < 4; ++mt)
            af[mt] = *(const bf16x8*)&As[mt * 16 + l15][quad * 8];
#pragma unroll
        for (int nt = 0; nt < 4; ++nt)
            bfv[nt] = *(const bf16x8*)&Bs[wave * 64 + nt * 16 + l15][quad * 8];
#pragma unroll
        for (int mt = 0; mt < 4; ++mt)
#pragma unroll
            for (int nt = 0; nt < 4; ++nt)
                acc[mt][nt] = __builtin_amdgcn_mfma_f32_16x16x32_bf16(
                    af[mt], bfv[nt], acc[mt][nt], 0, 0, 0);
        __syncthreads();
    }

#pragma unroll
    for (int mt = 0; mt < 4; ++mt) {
#pragma unroll
        for (int nt = 0; nt < 4; ++nt) {
            int gcol = wave * 64 + nt * 16 + l15;
#pragma unroll
            for (int r = 0; r < 4; ++r) {
                int grow = m0 + mt * 16 + quad * 4 + r;
                if (grow < M)
                    C[(size_t)grow * 256 + gcol] = f2bf(acc[mt][nt][r]);
            }
        }
    }
}

// ---- agg1b = bf16(relu(A h1b + b1)), F=256: wave/node, 4x edge unroll -----
__global__ __launch_bounds__(256) void agg256b_kernel(
    const uint2* __restrict__ h, const int2* __restrict__ ew,
    const int* __restrict__ row_ptr, const int* __restrict__ cnt,
    const float* __restrict__ bias, uint2* __restrict__ outb, int N) {
    const int node = blockIdx.x * 4 + (threadIdx.x >> 6);
    if (node >= N) return;
    const int lane = threadIdx.x & 63;

    float dv = rsqrtf((float)cnt[node] + 1.0f);
    float w0 = dv * dv;  // self-loop
    uint2 p = h[(size_t)node * 64 + lane];
    float4 acc;
    acc.x = bf2f_lo(p.x) * w0; acc.y = bf2f_hi(p.x) * w0;
    acc.z = bf2f_lo(p.y) * w0; acc.w = bf2f_hi(p.y) * w0;

    const int beg = row_ptr[node], end = row_ptr[node + 1];
    int e = beg;
    for (; e + 4 <= end; e += 4) {
        int2 p0 = ew[e];
        int2 p1 = ew[e + 1];
        int2 p2 = ew[e + 2];
        int2 p3 = ew[e + 3];
        uint2 q0 = h[(size_t)p0.x * 64 + lane];
        uint2 q1 = h[(size_t)p1.x * 64 + lane];
        uint2 q2 = h[(size_t)p2.x * 64 + lane];
        uint2 q3 = h[(size_t)p3.x * 64 + lane];
        float w0_ = __int_as_float(p0.y), w1_ = __int_as_float(p1.y);
        float w2_ = __int_as_float(p2.y), w3_ = __int_as_float(p3.y);
        acc.x += bf2f_lo(q0.x) * w0_ + bf2f_lo(q1.x) * w1_ +
                 bf2f_lo(q2.x) * w2_ + bf2f_lo(q3.x) * w3_;
        acc.y += bf2f_hi(q0.x) * w0_ + bf2f_hi(q1.x) * w1_ +
                 bf2f_hi(q2.x) * w2_ + bf2f_hi(q3.x) * w3_;
        acc.z += bf2f_lo(q0.y) * w0_ + bf2f_lo(q1.y) * w1_ +
                 bf2f_lo(q2.y) * w2_ + bf2f_lo(q3.y) * w3_;
        acc.w += bf2f_hi(q0.y) * w0_ + bf2f_hi(q1.y) * w1_ +
                 bf2f_hi(q2.y) * w2_ + bf2f_hi(q3.y) * w3_;
    }
    for (; e < end; ++e) {
        int2 pe = ew[e];
        float w = __int_as_float(pe.y);
        uint2 q = h[(size_t)pe.x * 64 + lane];
        acc.x += bf2f_lo(q.x) * w; acc.y += bf2f_hi(q.x) * w;
        acc.z += bf2f_lo(q.y) * w; acc.w += bf2f_hi(q.y) * w;
    }

    float4 b = *(const float4*)&bias[lane * 4];
    unsigned int o0 = f2bf(fmaxf(acc.x + b.x, 0.f));
    unsigned int o1 = f2bf(fmaxf(acc.y + b.y, 0.f));
    unsigned int o2 = f2bf(fmaxf(acc.z + b.z, 0.f));
    unsigned int o3 = f2bf(fmaxf(acc.w + b.w, 0.f));
    uint2 ov;
    ov.x = o0 | (o1 << 16);
    ov.y = o2 | (o3 << 16);
    outb[(size_t)node * 64 + lane] = ov;
}

// ---------------- GEMM2: h2b[M,64] = bf16(agg1b[M,256] @ W2), MFMA ----------
__global__ __launch_bounds__(256) void gemm2_kernel(
    const unsigned short* __restrict__ Ab, const unsigned short* __restrict__ Bt,
    unsigned short* __restrict__ C, int M) {
    __shared__ unsigned short As[64][32];
    __shared__ unsigned short Bs[64][32];

    const int tid = threadIdx.x;
    const int wave = tid >> 6, lane = tid & 63;
    const int quad = lane >> 4, l15 = lane & 15;
    const int m0 = blockIdx.x * 64;

    f32x4 acc[4] = {};

    const int arow = tid >> 2;
    const int akk = (tid & 3) << 3;
    const int gr = m0 + arow;
    const int bn = tid & 63, bkc = (tid >> 6) << 3;

    for (int k0 = 0; k0 < 256; k0 += 32) {
        bf16x8 av = {};
        if (gr < M) av = *(const bf16x8*)&Ab[(size_t)gr * 256 + k0 + akk];
        *(bf16x8*)&As[arow][akk] = av;
        *(bf16x8*)&Bs[bn][bkc] = *(const bf16x8*)&Bt[(size_t)bn * 256 + k0 + bkc];
        __syncthreads();

        bf16x8 af = *(const bf16x8*)&As[wave * 16 + l15][quad * 8];
#pragma unroll
        for (int nt = 0; nt < 4; ++nt) {
            bf16x8 bfv = *(const bf16x8*)&Bs[nt * 16 + l15][quad * 8];
            acc[nt] = __builtin_amdgcn_mfma_f32_16x16x32_bf16(af, bfv, acc[nt], 0, 0, 0);
        }
        __syncthreads();
    }

#pragma unroll
    for (int nt = 0; nt < 4; ++nt) {
#pragma unroll
        for (int r = 0; r < 4; ++r) {
            int grow = m0 + wave * 16 + quad * 4 + r;
            if (grow < M) C[(size_t)grow * 64 + nt * 16 + l15] = f2bf(acc[nt][r]);
        }
    }
}

// ---- out = log_softmax(A h2b + b2), F=64: wave/node, 4x edge unroll -------
__global__ __launch_bounds__(256) void agg64_kernel(
    const unsigned short* __restrict__ h, const int2* __restrict__ ew,
    const int* __restrict__ row_ptr, const int* __restrict__ cnt,
    const float* __restrict__ bias, float* __restrict__ out, int N) {
    const int d = blockIdx.x * 4 + (threadIdx.x >> 6);
    if (d >= N) return;
    const int lane = threadIdx.x & 63;

    float dv = rsqrtf((float)cnt[d] + 1.0f);
    float acc = bfu2f(h[(size_t)d * 64 + lane]) * dv * dv;

    const int beg = row_ptr[d], end = row_ptr[d + 1];
    int e = beg;
    for (; e + 4 <= end; e += 4) {
        int2 p0 = ew[e];
        int2 p1 = ew[e + 1];
        int2 p2 = ew[e + 2];
        int2 p3 = ew[e + 3];
        float v0 = bfu2f(h[(size_t)p0.x * 64 + lane]);
        float v1 = bfu2f(h[(size_t)p1.x * 64 + lane]);
        float v2 = bfu2f(h[(size_t)p2.x * 64 + lane]);
        float v3 = bfu2f(h[(size_t)p3.x * 64 + lane]);
        acc += v0 * __int_as_float(p0.y) + v1 * __int_as_float(p1.y) +
               v2 * __int_as_float(p2.y) + v3 * __int_as_float(p3.y);
    }
    for (; e < end; ++e) {
        int2 pe = ew[e];
        acc += bfu2f(h[(size_t)pe.x * 64 + lane]) * __int_as_float(pe.y);
    }

    float v = acc + bias[lane];
    float m = v;
#pragma unroll
    for (int off = 32; off > 0; off >>= 1) m = fmaxf(m, __shfl_xor(m, off, 64));
    float ex = expf(v - m);
    float ssum = ex;
#pragma unroll
    for (int off = 32; off > 0; off >>= 1) ssum += __shfl_xor(ssum, off, 64);
    out[(size_t)d * 64 + lane] = v - m - logf(ssum);
}

extern "C" void kernel_launch(void* const* d_in, const int* in_sizes, int n_in,
                              void* d_out, int out_size, void* d_ws, size_t ws_size,
                              hipStream_t stream) {
    const float* x  = (const float*)d_in[0];
    const int*   ei = (const int*)d_in[1];
    const float* W1 = (const float*)d_in[2];
    const float* b1 = (const float*)d_in[3];
    const float* W2 = (const float*)d_in[4];
    const float* b2 = (const float*)d_in[5];
    float* out = (float*)d_out;

    const int N = in_sizes[0] / 256;  // 100000
    const int E = in_sizes[1] / 2;    // 1600000
    const int NP = 102400;

    // Workspace layout (bytes; 16B-aligned segments). Total ~130 MB.
    char* ws = (char*)d_ws;
    int*   cnt     = (int*)ws;                 ws += (size_t)NP * 4;
    int*   cursor  = (int*)ws;                 ws += (size_t)NP * 4;
    int*   row_ptr = (int*)ws;                 ws += (size_t)(NP + 4) * 4;
    int2*  csr_ew  = (int2*)ws;                ws += (size_t)E * 8;
    unsigned short* W1t   = (unsigned short*)ws; ws += (size_t)256 * 256 * 2;
    unsigned short* W2t   = (unsigned short*)ws; ws += (size_t)256 * 64 * 2;
    unsigned short* h1b   = (unsigned short*)ws; ws += (size_t)N * 256 * 2;
    unsigned short* agg1b = (unsigned short*)ws; ws += (size_t)N * 256 * 2;
    unsigned short* h2b   = (unsigned short*)ws; ws += (size_t)N * 64 * 2;

    hipMemsetAsync(cnt, 0, (size_t)N * sizeof(int), stream);

    // CSR build
    deg_count_kernel<<<(E + 255) / 256, 256, 0, stream>>>(ei + E, E, cnt);
    scan_kernel<<<1, 1024, 0, stream>>>(cnt, row_ptr, cursor, N);
    scatter_kernel<<<(E + 255) / 256, 256, 0, stream>>>(
        ei, ei + E, cnt, cursor, csr_ew, E);

    // weight casts
    castw_kernel<<<(256 * 256 + 255) / 256, 256, 0, stream>>>(W1, W1t, 256, 256);
    castw_kernel<<<(256 * 64 + 255) / 256, 256, 0, stream>>>(W2, W2t, 256, 64);

    const int mblocks = (N + 63) / 64;

    // h1b = bf16(x @ W1)
    gemm1_kernel<<<mblocks, 256, 0, stream>>>(x, W1t, h1b, N);

    // agg1b = bf16(relu(A h1b + b1))
    agg256b_kernel<<<(N + 3) / 4, 256, 0, stream>>>(
        (const uint2*)h1b, csr_ew, row_ptr, cnt, b1, (uint2*)agg1b, N);

    // h2b = bf16(agg1b @ W2)
    gemm2_kernel<<<mblocks, 256, 0, stream>>>(agg1b, W2t, h2b, N);

    // out = log_softmax(A h2b + b2)
    agg64_kernel<<<(N + 3) / 4, 256, 0, stream>>>(
        h2b, csr_ew, row_ptr, cnt, b2, out, N);
}

// Round 5
// 598.528 us; speedup vs baseline: 4.2478x; 1.3653x over previous
//
#include <hip/hip_runtime.h>
#include <math.h>

// ---------------------------------------------------------------------------
// GCN 2-layer forward on MI355X. Round 5: hierarchical scan (the single-block
// scan was 230 us = 28% of runtime, latency-bound on 1 CU). Everything else
// unchanged from round 4.
// ---------------------------------------------------------------------------

typedef __attribute__((ext_vector_type(8))) short bf16x8;
typedef __attribute__((ext_vector_type(4))) float f32x4;

__device__ inline unsigned short f2bf(float f) {
    union { float f; unsigned int u; } v; v.f = f;
    unsigned int r = v.u + 0x7fffu + ((v.u >> 16) & 1u);  // RNE
    return (unsigned short)(r >> 16);
}
__device__ inline float bfu2f(unsigned short u) {
    union { unsigned int u; float f; } v; v.u = ((unsigned int)u) << 16; return v.f;
}
__device__ inline float bf2f_lo(unsigned int u) {
    union { unsigned int u; float f; } v; v.u = u << 16; return v.f;
}
__device__ inline float bf2f_hi(unsigned int u) {
    union { unsigned int u; float f; } v; v.u = u & 0xffff0000u; return v.f;
}

// ---------------- CSR build ----------------
__global__ __launch_bounds__(256) void deg_count_kernel(
    const int* __restrict__ dst, int E, int* __restrict__ cnt) {
    int e = blockIdx.x * blockDim.x + threadIdx.x;
    if (e < E) atomicAdd(&cnt[dst[e]], 1);
}

// --- hierarchical scan: 1024 elements per block ---
__global__ __launch_bounds__(256) void scan_part1_kernel(
    const int* __restrict__ cnt, int* __restrict__ bsum, int N) {
    __shared__ int s[256];
    const int tid = threadIdx.x;
    int base = blockIdx.x * 1024 + tid * 4;
    int v = 0;
#pragma unroll
    for (int j = 0; j < 4; ++j)
        if (base + j < N) v += cnt[base + j];
    s[tid] = v;
    __syncthreads();
    for (int off = 128; off > 0; off >>= 1) {
        if (tid < off) s[tid] += s[tid + off];
        __syncthreads();
    }
    if (tid == 0) bsum[blockIdx.x] = s[0];
}

// single small block: exclusive scan of NB block sums (NB <= 1024)
__global__ __launch_bounds__(1024) void scan_part2_kernel(
    const int* __restrict__ bsum, int* __restrict__ boffs, int NB,
    int* __restrict__ row_ptr, int N) {
    __shared__ int s[1024];
    const int tid = threadIdx.x;
    int v = (tid < NB) ? bsum[tid] : 0;
    s[tid] = v;
    __syncthreads();
    for (int off = 1; off < 1024; off <<= 1) {
        int t = (tid >= off) ? s[tid - off] : 0;
        __syncthreads();
        if (tid >= off) s[tid] += t;
        __syncthreads();
    }
    if (tid < NB) boffs[tid] = s[tid] - v;  // exclusive
    if (tid == 1023) row_ptr[N] = s[1023];  // grand total
}

__global__ __launch_bounds__(256) void scan_part3_kernel(
    const int* __restrict__ cnt, const int* __restrict__ boffs,
    int* __restrict__ row_ptr, int* __restrict__ cursor, int N) {
    __shared__ int s[256];
    const int tid = threadIdx.x;
    int base = blockIdx.x * 1024 + tid * 4;
    int c[4];
    int v = 0;
#pragma unroll
    for (int j = 0; j < 4; ++j) {
        c[j] = (base + j < N) ? cnt[base + j] : 0;
        v += c[j];
    }
    s[tid] = v;
    __syncthreads();
    for (int off = 1; off < 256; off <<= 1) {
        int t = (tid >= off) ? s[tid - off] : 0;
        __syncthreads();
        if (tid >= off) s[tid] += t;
        __syncthreads();
    }
    int run = boffs[blockIdx.x] + s[tid] - v;  // exclusive prefix for this thread
#pragma unroll
    for (int j = 0; j < 4; ++j) {
        if (base + j < N) {
            row_ptr[base + j] = run;
            cursor[base + j] = run;
            run += c[j];
        }
    }
}

__global__ __launch_bounds__(256) void scatter_kernel(
    const int* __restrict__ src, const int* __restrict__ dst,
    const int* __restrict__ cnt, int* __restrict__ cursor,
    int2* __restrict__ csr_ew, int E) {
    int e = blockIdx.x * blockDim.x + threadIdx.x;
    if (e >= E) return;
    int s = src[e], d = dst[e];
    float w = rsqrtf((float)cnt[s] + 1.0f) * rsqrtf((float)cnt[d] + 1.0f);
    int pos = atomicAdd(&cursor[d], 1);
    int2 rec;
    rec.x = s;
    rec.y = __float_as_int(w);
    csr_ew[pos] = rec;
}

// ---------------- weight cast+transpose: Wt[n][k] = bf16(W[k][n]) ----------
__global__ __launch_bounds__(256) void castw_kernel(
    const float* __restrict__ W, unsigned short* __restrict__ Wt,
    int K, int Ncol) {
    int i = blockIdx.x * 256 + threadIdx.x;
    if (i < K * Ncol) {
        int n = i / K;
        int k = i - n * K;
        Wt[i] = f2bf(W[(size_t)k * Ncol + n]);
    }
}

// ---------------- GEMM1: h1b[M,256] = bf16(x[M,256] @ W1), MFMA -------------
__global__ __launch_bounds__(256) void gemm1_kernel(
    const float* __restrict__ A, const unsigned short* __restrict__ Bt,
    unsigned short* __restrict__ C, int M) {
    __shared__ unsigned short As[64][32];
    __shared__ unsigned short Bs[256][32];

    const int tid = threadIdx.x;
    const int wave = tid >> 6, lane = tid & 63;
    const int quad = lane >> 4, l15 = lane & 15;
    const int m0 = blockIdx.x * 64;

    f32x4 acc[4][4] = {};

    const int arow = tid >> 2;
    const int akk = (tid & 3) << 3;
    const int gr = m0 + arow;

    for (int k0 = 0; k0 < 256; k0 += 32) {
        float4 a0 = make_float4(0.f, 0.f, 0.f, 0.f), a1 = a0;
        if (gr < M) {
            a0 = *(const float4*)&A[(size_t)gr * 256 + k0 + akk];
            a1 = *(const float4*)&A[(size_t)gr * 256 + k0 + akk + 4];
        }
        bf16x8 av;
        av[0] = (short)f2bf(a0.x); av[1] = (short)f2bf(a0.y);
        av[2] = (short)f2bf(a0.z); av[3] = (short)f2bf(a0.w);
        av[4] = (short)f2bf(a1.x); av[5] = (short)f2bf(a1.y);
        av[6] = (short)f2bf(a1.z); av[7] = (short)f2bf(a1.w);
        *(bf16x8*)&As[arow][akk] = av;

        const unsigned short* bsrc = &Bt[(size_t)tid * 256 + k0];
        *(bf16x8*)&Bs[tid][0]  = *(const bf16x8*)&bsrc[0];
        *(bf16x8*)&Bs[tid][8]  = *(const bf16x8*)&bsrc[8];
        *(bf16x8*)&Bs[tid][16] = *(const bf16x8*)&bsrc[16];
        *(bf16x8*)&Bs[tid][24] = *(const bf16x8*)&bsrc[24];
        __syncthreads();

        bf16x8 af[4], bfv[4];
#pragma unroll
        for (int mt = 0; mt < 4; ++mt)
            af[mt] = *(const bf16x8*)&As[mt * 16 + l15][quad * 8];
#pragma unroll
        for (int nt = 0; nt < 4; ++nt)
            bfv[nt] = *(const bf16x8*)&Bs[wave * 64 + nt * 16 + l15][quad * 8];
#pragma unroll
        for (int mt = 0; mt < 4; ++mt)
#pragma unroll
            for (int nt = 0; nt < 4; ++nt)
                acc[mt][nt] = __builtin_amdgcn_mfma_f32_16x16x32_bf16(
                    af[mt], bfv[nt], acc[mt][nt], 0, 0, 0);
        __syncthreads();
    }

#pragma unroll
    for (int mt = 0; mt < 4; ++mt) {
#pragma unroll
        for (int nt = 0; nt < 4; ++nt) {
            int gcol = wave * 64 + nt * 16 + l15;
#pragma unroll
            for (int r = 0; r < 4; ++r) {
                int grow = m0 + mt * 16 + quad * 4 + r;
                if (grow < M)
                    C[(size_t)grow * 256 + gcol] = f2bf(acc[mt][nt][r]);
            }
        }
    }
}

// ---- agg1b = bf16(relu(A h1b + b1)), F=256: wave/node, 4x edge unroll -----
__global__ __launch_bounds__(256) void agg256b_kernel(
    const uint2* __restrict__ h, const int2* __restrict__ ew,
    const int* __restrict__ row_ptr, const int* __restrict__ cnt,
    const float* __restrict__ bias, uint2* __restrict__ outb, int N) {
    const int node = blockIdx.x * 4 + (threadIdx.x >> 6);
    if (node >= N) return;
    const int lane = threadIdx.x & 63;

    float dv = rsqrtf((float)cnt[node] + 1.0f);
    float w0 = dv * dv;  // self-loop
    uint2 p = h[(size_t)node * 64 + lane];
    float4 acc;
    acc.x = bf2f_lo(p.x) * w0; acc.y = bf2f_hi(p.x) * w0;
    acc.z = bf2f_lo(p.y) * w0; acc.w = bf2f_hi(p.y) * w0;

    const int beg = row_ptr[node], end = row_ptr[node + 1];
    int e = beg;
    for (; e + 4 <= end; e += 4) {
        int2 p0 = ew[e];
        int2 p1 = ew[e + 1];
        int2 p2 = ew[e + 2];
        int2 p3 = ew[e + 3];
        uint2 q0 = h[(size_t)p0.x * 64 + lane];
        uint2 q1 = h[(size_t)p1.x * 64 + lane];
        uint2 q2 = h[(size_t)p2.x * 64 + lane];
        uint2 q3 = h[(size_t)p3.x * 64 + lane];
        float w0_ = __int_as_float(p0.y), w1_ = __int_as_float(p1.y);
        float w2_ = __int_as_float(p2.y), w3_ = __int_as_float(p3.y);
        acc.x += bf2f_lo(q0.x) * w0_ + bf2f_lo(q1.x) * w1_ +
                 bf2f_lo(q2.x) * w2_ + bf2f_lo(q3.x) * w3_;
        acc.y += bf2f_hi(q0.x) * w0_ + bf2f_hi(q1.x) * w1_ +
                 bf2f_hi(q2.x) * w2_ + bf2f_hi(q3.x) * w3_;
        acc.z += bf2f_lo(q0.y) * w0_ + bf2f_lo(q1.y) * w1_ +
                 bf2f_lo(q2.y) * w2_ + bf2f_lo(q3.y) * w3_;
        acc.w += bf2f_hi(q0.y) * w0_ + bf2f_hi(q1.y) * w1_ +
                 bf2f_hi(q2.y) * w2_ + bf2f_hi(q3.y) * w3_;
    }
    for (; e < end; ++e) {
        int2 pe = ew[e];
        float w = __int_as_float(pe.y);
        uint2 q = h[(size_t)pe.x * 64 + lane];
        acc.x += bf2f_lo(q.x) * w; acc.y += bf2f_hi(q.x) * w;
        acc.z += bf2f_lo(q.y) * w; acc.w += bf2f_hi(q.y) * w;
    }

    float4 b = *(const float4*)&bias[lane * 4];
    unsigned int o0 = f2bf(fmaxf(acc.x + b.x, 0.f));
    unsigned int o1 = f2bf(fmaxf(acc.y + b.y, 0.f));
    unsigned int o2 = f2bf(fmaxf(acc.z + b.z, 0.f));
    unsigned int o3 = f2bf(fmaxf(acc.w + b.w, 0.f));
    uint2 ov;
    ov.x = o0 | (o1 << 16);
    ov.y = o2 | (o3 << 16);
    outb[(size_t)node * 64 + lane] = ov;
}

// ---------------- GEMM2: h2b[M,64] = bf16(agg1b[M,256] @ W2), MFMA ----------
__global__ __launch_bounds__(256) void gemm2_kernel(
    const unsigned short* __restrict__ Ab, const unsigned short* __restrict__ Bt,
    unsigned short* __restrict__ C, int M) {
    __shared__ unsigned short As[64][32];
    __shared__ unsigned short Bs[64][32];

    const int tid = threadIdx.x;
    const int wave = tid >> 6, lane = tid & 63;
    const int quad = lane >> 4, l15 = lane & 15;
    const int m0 = blockIdx.x * 64;

    f32x4 acc[4] = {};

    const int arow = tid >> 2;
    const int akk = (tid & 3) << 3;
    const int gr = m0 + arow;
    const int bn = tid & 63, bkc = (tid >> 6) << 3;

    for (int k0 = 0; k0 < 256; k0 += 32) {
        bf16x8 av = {};
        if (gr < M) av = *(const bf16x8*)&Ab[(size_t)gr * 256 + k0 + akk];
        *(bf16x8*)&As[arow][akk] = av;
        *(bf16x8*)&Bs[bn][bkc] = *(const bf16x8*)&Bt[(size_t)bn * 256 + k0 + bkc];
        __syncthreads();

        bf16x8 af = *(const bf16x8*)&As[wave * 16 + l15][quad * 8];
#pragma unroll
        for (int nt = 0; nt < 4; ++nt) {
            bf16x8 bfv = *(const bf16x8*)&Bs[nt * 16 + l15][quad * 8];
            acc[nt] = __builtin_amdgcn_mfma_f32_16x16x32_bf16(af, bfv, acc[nt], 0, 0, 0);
        }
        __syncthreads();
    }

#pragma unroll
    for (int nt = 0; nt < 4; ++nt) {
#pragma unroll
        for (int r = 0; r < 4; ++r) {
            int grow = m0 + wave * 16 + quad * 4 + r;
            if (grow < M) C[(size_t)grow * 64 + nt * 16 + l15] = f2bf(acc[nt][r]);
        }
    }
}

// ---- out = log_softmax(A h2b + b2), F=64: wave/node, 4x edge unroll -------
__global__ __launch_bounds__(256) void agg64_kernel(
    const unsigned short* __restrict__ h, const int2* __restrict__ ew,
    const int* __restrict__ row_ptr, const int* __restrict__ cnt,
    const float* __restrict__ bias, float* __restrict__ out, int N) {
    const int d = blockIdx.x * 4 + (threadIdx.x >> 6);
    if (d >= N) return;
    const int lane = threadIdx.x & 63;

    float dv = rsqrtf((float)cnt[d] + 1.0f);
    float acc = bfu2f(h[(size_t)d * 64 + lane]) * dv * dv;

    const int beg = row_ptr[d], end = row_ptr[d + 1];
    int e = beg;
    for (; e + 4 <= end; e += 4) {
        int2 p0 = ew[e];
        int2 p1 = ew[e + 1];
        int2 p2 = ew[e + 2];
        int2 p3 = ew[e + 3];
        float v0 = bfu2f(h[(size_t)p0.x * 64 + lane]);
        float v1 = bfu2f(h[(size_t)p1.x * 64 + lane]);
        float v2 = bfu2f(h[(size_t)p2.x * 64 + lane]);
        float v3 = bfu2f(h[(size_t)p3.x * 64 + lane]);
        acc += v0 * __int_as_float(p0.y) + v1 * __int_as_float(p1.y) +
               v2 * __int_as_float(p2.y) + v3 * __int_as_float(p3.y);
    }
    for (; e < end; ++e) {
        int2 pe = ew[e];
        acc += bfu2f(h[(size_t)pe.x * 64 + lane]) * __int_as_float(pe.y);
    }

    float v = acc + bias[lane];
    float m = v;
#pragma unroll
    for (int off = 32; off > 0; off >>= 1) m = fmaxf(m, __shfl_xor(m, off, 64));
    float ex = expf(v - m);
    float ssum = ex;
#pragma unroll
    for (int off = 32; off > 0; off >>= 1) ssum += __shfl_xor(ssum, off, 64);
    out[(size_t)d * 64 + lane] = v - m - logf(ssum);
}

extern "C" void kernel_launch(void* const* d_in, const int* in_sizes, int n_in,
                              void* d_out, int out_size, void* d_ws, size_t ws_size,
                              hipStream_t stream) {
    const float* x  = (const float*)d_in[0];
    const int*   ei = (const int*)d_in[1];
    const float* W1 = (const float*)d_in[2];
    const float* b1 = (const float*)d_in[3];
    const float* W2 = (const float*)d_in[4];
    const float* b2 = (const float*)d_in[5];
    float* out = (float*)d_out;

    const int N = in_sizes[0] / 256;  // 100000
    const int E = in_sizes[1] / 2;    // 1600000
    const int NP = 102400;
    const int NB = (N + 1023) / 1024;  // scan blocks (98)

    // Workspace layout (bytes; 16B-aligned segments). Total ~130 MB.
    char* ws = (char*)d_ws;
    int*   cnt     = (int*)ws;                 ws += (size_t)NP * 4;
    int*   cursor  = (int*)ws;                 ws += (size_t)NP * 4;
    int*   row_ptr = (int*)ws;                 ws += (size_t)(NP + 4) * 4;
    int*   bsum    = (int*)ws;                 ws += (size_t)1024 * 4;
    int*   boffs   = (int*)ws;                 ws += (size_t)1024 * 4;
    int2*  csr_ew  = (int2*)ws;                ws += (size_t)E * 8;
    unsigned short* W1t   = (unsigned short*)ws; ws += (size_t)256 * 256 * 2;
    unsigned short* W2t   = (unsigned short*)ws; ws += (size_t)256 * 64 * 2;
    unsigned short* h1b   = (unsigned short*)ws; ws += (size_t)N * 256 * 2;
    unsigned short* agg1b = (unsigned short*)ws; ws += (size_t)N * 256 * 2;
    unsigned short* h2b   = (unsigned short*)ws; ws += (size_t)N * 64 * 2;

    hipMemsetAsync(cnt, 0, (size_t)N * sizeof(int), stream);

    // CSR build
    deg_count_kernel<<<(E + 255) / 256, 256, 0, stream>>>(ei + E, E, cnt);
    scan_part1_kernel<<<NB, 256, 0, stream>>>(cnt, bsum, N);
    scan_part2_kernel<<<1, 1024, 0, stream>>>(bsum, boffs, NB, row_ptr, N);
    scan_part3_kernel<<<NB, 256, 0, stream>>>(cnt, boffs, row_ptr, cursor, N);
    scatter_kernel<<<(E + 255) / 256, 256, 0, stream>>>(
        ei, ei + E, cnt, cursor, csr_ew, E);

    // weight casts
    castw_kernel<<<(256 * 256 + 255) / 256, 256, 0, stream>>>(W1, W1t, 256, 256);
    castw_kernel<<<(256 * 64 + 255) / 256, 256, 0, stream>>>(W2, W2t, 256, 64);

    const int mblocks = (N + 63) / 64;

    // h1b = bf16(x @ W1)
    gemm1_kernel<<<mblocks, 256, 0, stream>>>(x, W1t, h1b, N);

    // agg1b = bf16(relu(A h1b + b1))
    agg256b_kernel<<<(N + 3) / 4, 256, 0, stream>>>(
        (const uint2*)h1b, csr_ew, row_ptr, cnt, b1, (uint2*)agg1b, N);

    // h2b = bf16(agg1b @ W2)
    gemm2_kernel<<<mblocks, 256, 0, stream>>>(agg1b, W2t, h2b, N);

    // out = log_softmax(A h2b + b2)
    agg64_kernel<<<(N + 3) / 4, 256, 0, stream>>>(
        h2b, csr_ew, row_ptr, cnt, b2, out, N);
}

// Round 6
// 581.694 us; speedup vs baseline: 4.3707x; 1.0289x over previous
//
#include <hip/hip_runtime.h>
#include <math.h>

// ---------------------------------------------------------------------------
// GCN 2-layer forward on MI355X. Round 6: wide-gather aggregation.
//   agg256b: uint4/lane, 2 edges per wave-load, 8 rows in flight
//   agg64:   uint4/lane, 8 edges per wave-load, 16 rows in flight
//   (CSR build, MFMA GEMMs, hierarchical scan unchanged from round 5)
// ---------------------------------------------------------------------------

typedef __attribute__((ext_vector_type(8))) short bf16x8;
typedef __attribute__((ext_vector_type(4))) float f32x4;

__device__ inline unsigned short f2bf(float f) {
    union { float f; unsigned int u; } v; v.f = f;
    unsigned int r = v.u + 0x7fffu + ((v.u >> 16) & 1u);  // RNE
    return (unsigned short)(r >> 16);
}
__device__ inline float bf2f_lo(unsigned int u) {
    union { unsigned int u; float f; } v; v.u = u << 16; return v.f;
}
__device__ inline float bf2f_hi(unsigned int u) {
    union { unsigned int u; float f; } v; v.u = u & 0xffff0000u; return v.f;
}

// unpack uint4 (8 bf16) and FMA into acc[8] with weight w
__device__ inline void acc8(float* acc, uint4 q, float w) {
    acc[0] += bf2f_lo(q.x) * w; acc[1] += bf2f_hi(q.x) * w;
    acc[2] += bf2f_lo(q.y) * w; acc[3] += bf2f_hi(q.y) * w;
    acc[4] += bf2f_lo(q.z) * w; acc[5] += bf2f_hi(q.z) * w;
    acc[6] += bf2f_lo(q.w) * w; acc[7] += bf2f_hi(q.w) * w;
}

// ---------------- CSR build ----------------
__global__ __launch_bounds__(256) void deg_count_kernel(
    const int* __restrict__ dst, int E, int* __restrict__ cnt) {
    int e = blockIdx.x * blockDim.x + threadIdx.x;
    if (e < E) atomicAdd(&cnt[dst[e]], 1);
}

__global__ __launch_bounds__(256) void scan_part1_kernel(
    const int* __restrict__ cnt, int* __restrict__ bsum, int N) {
    __shared__ int s[256];
    const int tid = threadIdx.x;
    int base = blockIdx.x * 1024 + tid * 4;
    int v = 0;
#pragma unroll
    for (int j = 0; j < 4; ++j)
        if (base + j < N) v += cnt[base + j];
    s[tid] = v;
    __syncthreads();
    for (int off = 128; off > 0; off >>= 1) {
        if (tid < off) s[tid] += s[tid + off];
        __syncthreads();
    }
    if (tid == 0) bsum[blockIdx.x] = s[0];
}

__global__ __launch_bounds__(1024) void scan_part2_kernel(
    const int* __restrict__ bsum, int* __restrict__ boffs, int NB,
    int* __restrict__ row_ptr, int N) {
    __shared__ int s[1024];
    const int tid = threadIdx.x;
    int v = (tid < NB) ? bsum[tid] : 0;
    s[tid] = v;
    __syncthreads();
    for (int off = 1; off < 1024; off <<= 1) {
        int t = (tid >= off) ? s[tid - off] : 0;
        __syncthreads();
        if (tid >= off) s[tid] += t;
        __syncthreads();
    }
    if (tid < NB) boffs[tid] = s[tid] - v;  // exclusive
    if (tid == 1023) row_ptr[N] = s[1023];  // grand total
}

__global__ __launch_bounds__(256) void scan_part3_kernel(
    const int* __restrict__ cnt, const int* __restrict__ boffs,
    int* __restrict__ row_ptr, int* __restrict__ cursor, int N) {
    __shared__ int s[256];
    const int tid = threadIdx.x;
    int base = blockIdx.x * 1024 + tid * 4;
    int c[4];
    int v = 0;
#pragma unroll
    for (int j = 0; j < 4; ++j) {
        c[j] = (base + j < N) ? cnt[base + j] : 0;
        v += c[j];
    }
    s[tid] = v;
    __syncthreads();
    for (int off = 1; off < 256; off <<= 1) {
        int t = (tid >= off) ? s[tid - off] : 0;
        __syncthreads();
        if (tid >= off) s[tid] += t;
        __syncthreads();
    }
    int run = boffs[blockIdx.x] + s[tid] - v;
#pragma unroll
    for (int j = 0; j < 4; ++j) {
        if (base + j < N) {
            row_ptr[base + j] = run;
            cursor[base + j] = run;
            run += c[j];
        }
    }
}

__global__ __launch_bounds__(256) void scatter_kernel(
    const int* __restrict__ src, const int* __restrict__ dst,
    const int* __restrict__ cnt, int* __restrict__ cursor,
    int2* __restrict__ csr_ew, int E) {
    int e = blockIdx.x * blockDim.x + threadIdx.x;
    if (e >= E) return;
    int s = src[e], d = dst[e];
    float w = rsqrtf((float)cnt[s] + 1.0f) * rsqrtf((float)cnt[d] + 1.0f);
    int pos = atomicAdd(&cursor[d], 1);
    int2 rec;
    rec.x = s;
    rec.y = __float_as_int(w);
    csr_ew[pos] = rec;
}

// ---------------- weight cast+transpose: Wt[n][k] = bf16(W[k][n]) ----------
__global__ __launch_bounds__(256) void castw_kernel(
    const float* __restrict__ W, unsigned short* __restrict__ Wt,
    int K, int Ncol) {
    int i = blockIdx.x * 256 + threadIdx.x;
    if (i < K * Ncol) {
        int n = i / K;
        int k = i - n * K;
        Wt[i] = f2bf(W[(size_t)k * Ncol + n]);
    }
}

// ---------------- GEMM1: h1b[M,256] = bf16(x[M,256] @ W1), MFMA -------------
__global__ __launch_bounds__(256) void gemm1_kernel(
    const float* __restrict__ A, const unsigned short* __restrict__ Bt,
    unsigned short* __restrict__ C, int M) {
    __shared__ unsigned short As[64][32];
    __shared__ unsigned short Bs[256][32];

    const int tid = threadIdx.x;
    const int wave = tid >> 6, lane = tid & 63;
    const int quad = lane >> 4, l15 = lane & 15;
    const int m0 = blockIdx.x * 64;

    f32x4 acc[4][4] = {};

    const int arow = tid >> 2;
    const int akk = (tid & 3) << 3;
    const int gr = m0 + arow;

    for (int k0 = 0; k0 < 256; k0 += 32) {
        float4 a0 = make_float4(0.f, 0.f, 0.f, 0.f), a1 = a0;
        if (gr < M) {
            a0 = *(const float4*)&A[(size_t)gr * 256 + k0 + akk];
            a1 = *(const float4*)&A[(size_t)gr * 256 + k0 + akk + 4];
        }
        bf16x8 av;
        av[0] = (short)f2bf(a0.x); av[1] = (short)f2bf(a0.y);
        av[2] = (short)f2bf(a0.z); av[3] = (short)f2bf(a0.w);
        av[4] = (short)f2bf(a1.x); av[5] = (short)f2bf(a1.y);
        av[6] = (short)f2bf(a1.z); av[7] = (short)f2bf(a1.w);
        *(bf16x8*)&As[arow][akk] = av;

        const unsigned short* bsrc = &Bt[(size_t)tid * 256 + k0];
        *(bf16x8*)&Bs[tid][0]  = *(const bf16x8*)&bsrc[0];
        *(bf16x8*)&Bs[tid][8]  = *(const bf16x8*)&bsrc[8];
        *(bf16x8*)&Bs[tid][16] = *(const bf16x8*)&bsrc[16];
        *(bf16x8*)&Bs[tid][24] = *(const bf16x8*)&bsrc[24];
        __syncthreads();

        bf16x8 af[4], bfv[4];
#pragma unroll
        for (int mt = 0; mt < 4; ++mt)
            af[mt] = *(const bf16x8*)&As[mt * 16 + l15][quad * 8];
#pragma unroll
        for (int nt = 0; nt < 4; ++nt)
            bfv[nt] = *(const bf16x8*)&Bs[wave * 64 + nt * 16 + l15][quad * 8];
#pragma unroll
        for (int mt = 0; mt < 4; ++mt)
#pragma unroll
            for (int nt = 0; nt < 4; ++nt)
                acc[mt][nt] = __builtin_amdgcn_mfma_f32_16x16x32_bf16(
                    af[mt], bfv[nt], acc[mt][nt], 0, 0, 0);
        __syncthreads();
    }

#pragma unroll
    for (int mt = 0; mt < 4; ++mt) {
#pragma unroll
        for (int nt = 0; nt < 4; ++nt) {
            int gcol = wave * 64 + nt * 16 + l15;
#pragma unroll
            for (int r = 0; r < 4; ++r) {
                int grow = m0 + mt * 16 + quad * 4 + r;
                if (grow < M)
                    C[(size_t)grow * 256 + gcol] = f2bf(acc[mt][nt][r]);
            }
        }
    }
}

// ---- agg1b = bf16(relu(A h1b + b1)), F=256 --------------------------------
// Wave per node. Lane = (half: which edge of a pair, c: 16B chunk of row).
// 2 edges per load instruction, unroll 4 -> 8 rows in flight.
__global__ __launch_bounds__(256) void agg256b_kernel(
    const uint4* __restrict__ h,  // row = 32 uint4 (256 bf16)
    const int2* __restrict__ ew,
    const int* __restrict__ row_ptr, const int* __restrict__ cnt,
    const float* __restrict__ bias, uint4* __restrict__ outb, int N) {
    const int node = blockIdx.x * 4 + (threadIdx.x >> 6);
    if (node >= N) return;
    const int lane = threadIdx.x & 63;
    const int half = lane >> 5;
    const int c = lane & 31;

    float dv = rsqrtf((float)cnt[node] + 1.0f);
    float w0 = dv * dv;

    float acc[8] = {0.f, 0.f, 0.f, 0.f, 0.f, 0.f, 0.f, 0.f};
    {   // self-loop: half 0 carries the weight, half 1 contributes 0
        uint4 q = h[(size_t)node * 32 + c];
        acc8(acc, q, half == 0 ? w0 : 0.f);
    }

    const int beg = row_ptr[node], end = row_ptr[node + 1];
    int e = beg;
    for (; e + 8 <= end; e += 8) {
        int2 r0 = ew[e + 0 + half];
        int2 r1 = ew[e + 2 + half];
        int2 r2 = ew[e + 4 + half];
        int2 r3 = ew[e + 6 + half];
        uint4 q0 = h[(size_t)r0.x * 32 + c];
        uint4 q1 = h[(size_t)r1.x * 32 + c];
        uint4 q2 = h[(size_t)r2.x * 32 + c];
        uint4 q3 = h[(size_t)r3.x * 32 + c];
        acc8(acc, q0, __int_as_float(r0.y));
        acc8(acc, q1, __int_as_float(r1.y));
        acc8(acc, q2, __int_as_float(r2.y));
        acc8(acc, q3, __int_as_float(r3.y));
    }
    for (; e < end; e += 2) {
        int idx = e + half;
        int idxc = min(idx, end - 1);
        int2 r = ew[idxc];
        float w = (idx < end) ? __int_as_float(r.y) : 0.f;
        uint4 q = h[(size_t)r.x * 32 + c];
        acc8(acc, q, w);
    }

    // combine the two edge streams
#pragma unroll
    for (int k = 0; k < 8; ++k) acc[k] += __shfl_xor(acc[k], 32, 64);

    if (half == 0) {
        float4 b0 = *(const float4*)&bias[c * 8];
        float4 b1 = *(const float4*)&bias[c * 8 + 4];
        unsigned int o0 = f2bf(fmaxf(acc[0] + b0.x, 0.f));
        unsigned int o1 = f2bf(fmaxf(acc[1] + b0.y, 0.f));
        unsigned int o2 = f2bf(fmaxf(acc[2] + b0.z, 0.f));
        unsigned int o3 = f2bf(fmaxf(acc[3] + b0.w, 0.f));
        unsigned int o4 = f2bf(fmaxf(acc[4] + b1.x, 0.f));
        unsigned int o5 = f2bf(fmaxf(acc[5] + b1.y, 0.f));
        unsigned int o6 = f2bf(fmaxf(acc[6] + b1.z, 0.f));
        unsigned int o7 = f2bf(fmaxf(acc[7] + b1.w, 0.f));
        uint4 ov;
        ov.x = o0 | (o1 << 16);
        ov.y = o2 | (o3 << 16);
        ov.z = o4 | (o5 << 16);
        ov.w = o6 | (o7 << 16);
        outb[(size_t)node * 32 + c] = ov;
    }
}

// ---------------- GEMM2: h2b[M,64] = bf16(agg1b[M,256] @ W2), MFMA ----------
__global__ __launch_bounds__(256) void gemm2_kernel(
    const unsigned short* __restrict__ Ab, const unsigned short* __restrict__ Bt,
    unsigned short* __restrict__ C, int M) {
    __shared__ unsigned short As[64][32];
    __shared__ unsigned short Bs[64][32];

    const int tid = threadIdx.x;
    const int wave = tid >> 6, lane = tid & 63;
    const int quad = lane >> 4, l15 = lane & 15;
    const int m0 = blockIdx.x * 64;

    f32x4 acc[4] = {};

    const int arow = tid >> 2;
    const int akk = (tid & 3) << 3;
    const int gr = m0 + arow;
    const int bn = tid & 63, bkc = (tid >> 6) << 3;

    for (int k0 = 0; k0 < 256; k0 += 32) {
        bf16x8 av = {};
        if (gr < M) av = *(const bf16x8*)&Ab[(size_t)gr * 256 + k0 + akk];
        *(bf16x8*)&As[arow][akk] = av;
        *(bf16x8*)&Bs[bn][bkc] = *(const bf16x8*)&Bt[(size_t)bn * 256 + k0 + bkc];
        __syncthreads();

        bf16x8 af = *(const bf16x8*)&As[wave * 16 + l15][quad * 8];
#pragma unroll
        for (int nt = 0; nt < 4; ++nt) {
            bf16x8 bfv = *(const bf16x8*)&Bs[nt * 16 + l15][quad * 8];
            acc[nt] = __builtin_amdgcn_mfma_f32_16x16x32_bf16(af, bfv, acc[nt], 0, 0, 0);
        }
        __syncthreads();
    }

#pragma unroll
    for (int nt = 0; nt < 4; ++nt) {
#pragma unroll
        for (int r = 0; r < 4; ++r) {
            int grow = m0 + wave * 16 + quad * 4 + r;
            if (grow < M) C[(size_t)grow * 64 + nt * 16 + l15] = f2bf(acc[nt][r]);
        }
    }
}

// ---- out = log_softmax(A h2b + b2), F=64 ----------------------------------
// Wave per node. Lane = (g: edge in group of 8, c: 16B chunk of 128B row).
// 8 edges per load instruction, unroll 2 -> 16 rows in flight.
__global__ __launch_bounds__(256) void agg64_kernel(
    const uint4* __restrict__ h,  // row = 8 uint4 (64 bf16)
    const int2* __restrict__ ew, const int* __restrict__ row_ptr,
    const int* __restrict__ cnt, const float* __restrict__ bias,
    float* __restrict__ out, int N) {
    const int node = blockIdx.x * 4 + (threadIdx.x >> 6);
    if (node >= N) return;
    const int lane = threadIdx.x & 63;
    const int g = lane >> 3;
    const int c = lane & 7;

    float dv = rsqrtf((float)cnt[node] + 1.0f);
    float w0 = dv * dv;

    float acc[8] = {0.f, 0.f, 0.f, 0.f, 0.f, 0.f, 0.f, 0.f};
    {   // self-loop on group 0 only
        uint4 q = h[(size_t)node * 8 + c];
        acc8(acc, q, g == 0 ? w0 : 0.f);
    }

    const int beg = row_ptr[node], end = row_ptr[node + 1];
    int e = beg;
    for (; e + 16 <= end; e += 16) {
        int2 r0 = ew[e + g];
        int2 r1 = ew[e + 8 + g];
        uint4 q0 = h[(size_t)r0.x * 8 + c];
        uint4 q1 = h[(size_t)r1.x * 8 + c];
        acc8(acc, q0, __int_as_float(r0.y));
        acc8(acc, q1, __int_as_float(r1.y));
    }
    for (; e < end; e += 8) {
        int idx = e + g;
        int idxc = min(idx, end - 1);
        int2 r = ew[idxc];
        float w = (idx < end) ? __int_as_float(r.y) : 0.f;
        uint4 q = h[(size_t)r.x * 8 + c];
        acc8(acc, q, w);
    }

    // reduce across the 8 edge groups (bits 3,4,5 of lane)
#pragma unroll
    for (int k = 0; k < 8; ++k) {
        acc[k] += __shfl_xor(acc[k], 8, 64);
        acc[k] += __shfl_xor(acc[k], 16, 64);
        acc[k] += __shfl_xor(acc[k], 32, 64);
    }

    // bias
    float4 b0 = *(const float4*)&bias[c * 8];
    float4 b1 = *(const float4*)&bias[c * 8 + 4];
    float v[8];
    v[0] = acc[0] + b0.x; v[1] = acc[1] + b0.y;
    v[2] = acc[2] + b0.z; v[3] = acc[3] + b0.w;
    v[4] = acc[4] + b1.x; v[5] = acc[5] + b1.y;
    v[6] = acc[6] + b1.z; v[7] = acc[7] + b1.w;

    // log_softmax across 64 features: local 8 + shfl over c (bits 0..2)
    float m = v[0];
#pragma unroll
    for (int k = 1; k < 8; ++k) m = fmaxf(m, v[k]);
    m = fmaxf(m, __shfl_xor(m, 1, 64));
    m = fmaxf(m, __shfl_xor(m, 2, 64));
    m = fmaxf(m, __shfl_xor(m, 4, 64));
    float s = 0.f;
#pragma unroll
    for (int k = 0; k < 8; ++k) s += expf(v[k] - m);
    s += __shfl_xor(s, 1, 64);
    s += __shfl_xor(s, 2, 64);
    s += __shfl_xor(s, 4, 64);
    float ls = m + logf(s);

    if (g == 0) {
        float4 o0, o1;
        o0.x = v[0] - ls; o0.y = v[1] - ls; o0.z = v[2] - ls; o0.w = v[3] - ls;
        o1.x = v[4] - ls; o1.y = v[5] - ls; o1.z = v[6] - ls; o1.w = v[7] - ls;
        *(float4*)&out[(size_t)node * 64 + c * 8] = o0;
        *(float4*)&out[(size_t)node * 64 + c * 8 + 4] = o1;
    }
}

extern "C" void kernel_launch(void* const* d_in, const int* in_sizes, int n_in,
                              void* d_out, int out_size, void* d_ws, size_t ws_size,
                              hipStream_t stream) {
    const float* x  = (const float*)d_in[0];
    const int*   ei = (const int*)d_in[1];
    const float* W1 = (const float*)d_in[2];
    const float* b1 = (const float*)d_in[3];
    const float* W2 = (const float*)d_in[4];
    const float* b2 = (const float*)d_in[5];
    float* out = (float*)d_out;

    const int N = in_sizes[0] / 256;  // 100000
    const int E = in_sizes[1] / 2;    // 1600000
    const int NP = 102400;
    const int NB = (N + 1023) / 1024;  // scan blocks (98)

    // Workspace layout (bytes; 16B-aligned segments). Total ~130 MB.
    char* ws = (char*)d_ws;
    int*   cnt     = (int*)ws;                 ws += (size_t)NP * 4;
    int*   cursor  = (int*)ws;                 ws += (size_t)NP * 4;
    int*   row_ptr = (int*)ws;                 ws += (size_t)(NP + 4) * 4;
    int*   bsum    = (int*)ws;                 ws += (size_t)1024 * 4;
    int*   boffs   = (int*)ws;                 ws += (size_t)1024 * 4;
    int2*  csr_ew  = (int2*)ws;                ws += (size_t)E * 8;
    unsigned short* W1t   = (unsigned short*)ws; ws += (size_t)256 * 256 * 2;
    unsigned short* W2t   = (unsigned short*)ws; ws += (size_t)256 * 64 * 2;
    unsigned short* h1b   = (unsigned short*)ws; ws += (size_t)N * 256 * 2;
    unsigned short* agg1b = (unsigned short*)ws; ws += (size_t)N * 256 * 2;
    unsigned short* h2b   = (unsigned short*)ws; ws += (size_t)N * 64 * 2;

    hipMemsetAsync(cnt, 0, (size_t)N * sizeof(int), stream);

    // CSR build
    deg_count_kernel<<<(E + 255) / 256, 256, 0, stream>>>(ei + E, E, cnt);
    scan_part1_kernel<<<NB, 256, 0, stream>>>(cnt, bsum, N);
    scan_part2_kernel<<<1, 1024, 0, stream>>>(bsum, boffs, NB, row_ptr, N);
    scan_part3_kernel<<<NB, 256, 0, stream>>>(cnt, boffs, row_ptr, cursor, N);
    scatter_kernel<<<(E + 255) / 256, 256, 0, stream>>>(
        ei, ei + E, cnt, cursor, csr_ew, E);

    // weight casts
    castw_kernel<<<(256 * 256 + 255) / 256, 256, 0, stream>>>(W1, W1t, 256, 256);
    castw_kernel<<<(256 * 64 + 255) / 256, 256, 0, stream>>>(W2, W2t, 256, 64);

    const int mblocks = (N + 63) / 64;

    // h1b = bf16(x @ W1)
    gemm1_kernel<<<mblocks, 256, 0, stream>>>(x, W1t, h1b, N);

    // agg1b = bf16(relu(A h1b + b1))
    agg256b_kernel<<<(N + 3) / 4, 256, 0, stream>>>(
        (const uint4*)h1b, csr_ew, row_ptr, cnt, b1, (uint4*)agg1b, N);

    // h2b = bf16(agg1b @ W2)
    gemm2_kernel<<<mblocks, 256, 0, stream>>>(agg1b, W2t, h2b, N);

    // out = log_softmax(A h2b + b2)
    agg64_kernel<<<(N + 3) / 4, 256, 0, stream>>>(
        (const uint4*)h2b, csr_ew, row_ptr, cnt, b2, out, N);
}

// Round 7
// 554.351 us; speedup vs baseline: 4.5863x; 1.0493x over previous
//
#include <hip/hip_runtime.h>
#include <math.h>

// ---------------------------------------------------------------------------
// GCN 2-layer forward on MI355X. Round 7:
//   - CSR build: rank trick (deg pass atomicAdd return = slot) -> scatter has
//     NO atomics; cursor array gone
//   - gemm1: 128-row tile (B staging + barriers amortized 2x)
//   - merged weight-cast kernel
//   agg256b/agg64 unchanged (at their gather-path ceiling).
// ---------------------------------------------------------------------------

typedef __attribute__((ext_vector_type(8))) short bf16x8;
typedef __attribute__((ext_vector_type(4))) float f32x4;

__device__ inline unsigned short f2bf(float f) {
    union { float f; unsigned int u; } v; v.f = f;
    unsigned int r = v.u + 0x7fffu + ((v.u >> 16) & 1u);  // RNE
    return (unsigned short)(r >> 16);
}
__device__ inline float bf2f_lo(unsigned int u) {
    union { unsigned int u; float f; } v; v.u = u << 16; return v.f;
}
__device__ inline float bf2f_hi(unsigned int u) {
    union { unsigned int u; float f; } v; v.u = u & 0xffff0000u; return v.f;
}

// unpack uint4 (8 bf16) and FMA into acc[8] with weight w
__device__ inline void acc8(float* acc, uint4 q, float w) {
    acc[0] += bf2f_lo(q.x) * w; acc[1] += bf2f_hi(q.x) * w;
    acc[2] += bf2f_lo(q.y) * w; acc[3] += bf2f_hi(q.y) * w;
    acc[4] += bf2f_lo(q.z) * w; acc[5] += bf2f_hi(q.z) * w;
    acc[6] += bf2f_lo(q.w) * w; acc[7] += bf2f_hi(q.w) * w;
}

// ---------------- CSR build ----------------
// Degree count; atomicAdd's return value is this edge's rank within its row.
__global__ __launch_bounds__(256) void deg_rank_kernel(
    const int* __restrict__ dst, int E, int* __restrict__ cnt,
    int* __restrict__ rank) {
    int e = blockIdx.x * blockDim.x + threadIdx.x;
    if (e < E) rank[e] = atomicAdd(&cnt[dst[e]], 1);
}

__global__ __launch_bounds__(256) void scan_part1_kernel(
    const int* __restrict__ cnt, int* __restrict__ bsum, int N) {
    __shared__ int s[256];
    const int tid = threadIdx.x;
    int base = blockIdx.x * 1024 + tid * 4;
    int v = 0;
#pragma unroll
    for (int j = 0; j < 4; ++j)
        if (base + j < N) v += cnt[base + j];
    s[tid] = v;
    __syncthreads();
    for (int off = 128; off > 0; off >>= 1) {
        if (tid < off) s[tid] += s[tid + off];
        __syncthreads();
    }
    if (tid == 0) bsum[blockIdx.x] = s[0];
}

__global__ __launch_bounds__(1024) void scan_part2_kernel(
    const int* __restrict__ bsum, int* __restrict__ boffs, int NB,
    int* __restrict__ row_ptr, int N) {
    __shared__ int s[1024];
    const int tid = threadIdx.x;
    int v = (tid < NB) ? bsum[tid] : 0;
    s[tid] = v;
    __syncthreads();
    for (int off = 1; off < 1024; off <<= 1) {
        int t = (tid >= off) ? s[tid - off] : 0;
        __syncthreads();
        if (tid >= off) s[tid] += t;
        __syncthreads();
    }
    if (tid < NB) boffs[tid] = s[tid] - v;  // exclusive
    if (tid == 1023) row_ptr[N] = s[1023];  // grand total
}

__global__ __launch_bounds__(256) void scan_part3_kernel(
    const int* __restrict__ cnt, const int* __restrict__ boffs,
    int* __restrict__ row_ptr, int N) {
    __shared__ int s[256];
    const int tid = threadIdx.x;
    int base = blockIdx.x * 1024 + tid * 4;
    int c[4];
    int v = 0;
#pragma unroll
    for (int j = 0; j < 4; ++j) {
        c[j] = (base + j < N) ? cnt[base + j] : 0;
        v += c[j];
    }
    s[tid] = v;
    __syncthreads();
    for (int off = 1; off < 256; off <<= 1) {
        int t = (tid >= off) ? s[tid - off] : 0;
        __syncthreads();
        if (tid >= off) s[tid] += t;
        __syncthreads();
    }
    int run = boffs[blockIdx.x] + s[tid] - v;
#pragma unroll
    for (int j = 0; j < 4; ++j) {
        if (base + j < N) {
            row_ptr[base + j] = run;
            run += c[j];
        }
    }
}

// Atomic-free scatter: slot = row_ptr[dst] + rank.
__global__ __launch_bounds__(256) void scatter_kernel(
    const int* __restrict__ src, const int* __restrict__ dst,
    const int* __restrict__ rank, const int* __restrict__ cnt,
    const int* __restrict__ row_ptr, int2* __restrict__ csr_ew, int E) {
    int e = blockIdx.x * blockDim.x + threadIdx.x;
    if (e >= E) return;
    int s = src[e], d = dst[e];
    float w = rsqrtf((float)cnt[s] + 1.0f) * rsqrtf((float)cnt[d] + 1.0f);
    int pos = row_ptr[d] + rank[e];
    int2 rec;
    rec.x = s;
    rec.y = __float_as_int(w);
    csr_ew[pos] = rec;
}

// ------ merged weight cast+transpose: W1t[n][k], W2t[n][k] (bf16) ----------
__global__ __launch_bounds__(256) void castw_kernel(
    const float* __restrict__ W1, const float* __restrict__ W2,
    unsigned short* __restrict__ W1t, unsigned short* __restrict__ W2t) {
    int i = blockIdx.x * 256 + threadIdx.x;
    if (i < 65536) {  // W1: 256x256
        int n = i >> 8, k = i & 255;
        W1t[i] = f2bf(W1[(size_t)k * 256 + n]);
    } else if (i < 65536 + 16384) {  // W2: 256x64 -> W2t[64][256]
        int j = i - 65536;
        int n = j >> 8, k = j & 255;
        W2t[j] = f2bf(W2[(size_t)k * 64 + n]);
    }
}

// ---------------- GEMM1: h1b[M,256] = bf16(x[M,256] @ W1), MFMA -------------
// 128(M) x 256(N) tile, BK=32. Wave w owns cols [64w, 64w+64). 32 MFMA/iter/wave.
__global__ __launch_bounds__(256) void gemm1_kernel(
    const float* __restrict__ A, const unsigned short* __restrict__ Bt,
    unsigned short* __restrict__ C, int M) {
    __shared__ unsigned short As[128][32];   // 8 KB
    __shared__ unsigned short Bs[256][32];   // 16 KB

    const int tid = threadIdx.x;
    const int wave = tid >> 6, lane = tid & 63;
    const int quad = lane >> 4, l15 = lane & 15;
    const int m0 = blockIdx.x * 128;

    f32x4 acc[8][4] = {};

    const int arow = tid >> 1;          // 0..127
    const int akk  = (tid & 1) << 4;    // 0 or 16
    const int gr = m0 + arow;

    for (int k0 = 0; k0 < 256; k0 += 32) {
        // stage A: thread loads 16 fp32, casts to 16 bf16
        float4 a0 = make_float4(0.f,0.f,0.f,0.f), a1 = a0, a2 = a0, a3 = a0;
        if (gr < M) {
            const float* ap = &A[(size_t)gr * 256 + k0 + akk];
            a0 = *(const float4*)&ap[0];
            a1 = *(const float4*)&ap[4];
            a2 = *(const float4*)&ap[8];
            a3 = *(const float4*)&ap[12];
        }
        bf16x8 av0, av1;
        av0[0] = (short)f2bf(a0.x); av0[1] = (short)f2bf(a0.y);
        av0[2] = (short)f2bf(a0.z); av0[3] = (short)f2bf(a0.w);
        av0[4] = (short)f2bf(a1.x); av0[5] = (short)f2bf(a1.y);
        av0[6] = (short)f2bf(a1.z); av0[7] = (short)f2bf(a1.w);
        av1[0] = (short)f2bf(a2.x); av1[1] = (short)f2bf(a2.y);
        av1[2] = (short)f2bf(a2.z); av1[3] = (short)f2bf(a2.w);
        av1[4] = (short)f2bf(a3.x); av1[5] = (short)f2bf(a3.y);
        av1[6] = (short)f2bf(a3.z); av1[7] = (short)f2bf(a3.w);
        *(bf16x8*)&As[arow][akk]     = av0;
        *(bf16x8*)&As[arow][akk + 8] = av1;

        // stage B: thread loads 32 bf16 of Wt row `tid`
        const unsigned short* bsrc = &Bt[(size_t)tid * 256 + k0];
        *(bf16x8*)&Bs[tid][0]  = *(const bf16x8*)&bsrc[0];
        *(bf16x8*)&Bs[tid][8]  = *(const bf16x8*)&bsrc[8];
        *(bf16x8*)&Bs[tid][16] = *(const bf16x8*)&bsrc[16];
        *(bf16x8*)&Bs[tid][24] = *(const bf16x8*)&bsrc[24];
        __syncthreads();

        bf16x8 bfv[4];
#pragma unroll
        for (int nt = 0; nt < 4; ++nt)
            bfv[nt] = *(const bf16x8*)&Bs[wave * 64 + nt * 16 + l15][quad * 8];
#pragma unroll
        for (int mt = 0; mt < 8; ++mt) {
            bf16x8 af = *(const bf16x8*)&As[mt * 16 + l15][quad * 8];
#pragma unroll
            for (int nt = 0; nt < 4; ++nt)
                acc[mt][nt] = __builtin_amdgcn_mfma_f32_16x16x32_bf16(
                    af, bfv[nt], acc[mt][nt], 0, 0, 0);
        }
        __syncthreads();
    }

#pragma unroll
    for (int mt = 0; mt < 8; ++mt) {
#pragma unroll
        for (int nt = 0; nt < 4; ++nt) {
            int gcol = wave * 64 + nt * 16 + l15;
#pragma unroll
            for (int r = 0; r < 4; ++r) {
                int grow = m0 + mt * 16 + quad * 4 + r;
                if (grow < M)
                    C[(size_t)grow * 256 + gcol] = f2bf(acc[mt][nt][r]);
            }
        }
    }
}

// ---- agg1b = bf16(relu(A h1b + b1)), F=256 --------------------------------
__global__ __launch_bounds__(256) void agg256b_kernel(
    const uint4* __restrict__ h,  // row = 32 uint4 (256 bf16)
    const int2* __restrict__ ew,
    const int* __restrict__ row_ptr, const int* __restrict__ cnt,
    const float* __restrict__ bias, uint4* __restrict__ outb, int N) {
    const int node = blockIdx.x * 4 + (threadIdx.x >> 6);
    if (node >= N) return;
    const int lane = threadIdx.x & 63;
    const int half = lane >> 5;
    const int c = lane & 31;

    float dv = rsqrtf((float)cnt[node] + 1.0f);
    float w0 = dv * dv;

    float acc[8] = {0.f, 0.f, 0.f, 0.f, 0.f, 0.f, 0.f, 0.f};
    {
        uint4 q = h[(size_t)node * 32 + c];
        acc8(acc, q, half == 0 ? w0 : 0.f);
    }

    const int beg = row_ptr[node], end = row_ptr[node + 1];
    int e = beg;
    for (; e + 8 <= end; e += 8) {
        int2 r0 = ew[e + 0 + half];
        int2 r1 = ew[e + 2 + half];
        int2 r2 = ew[e + 4 + half];
        int2 r3 = ew[e + 6 + half];
        uint4 q0 = h[(size_t)r0.x * 32 + c];
        uint4 q1 = h[(size_t)r1.x * 32 + c];
        uint4 q2 = h[(size_t)r2.x * 32 + c];
        uint4 q3 = h[(size_t)r3.x * 32 + c];
        acc8(acc, q0, __int_as_float(r0.y));
        acc8(acc, q1, __int_as_float(r1.y));
        acc8(acc, q2, __int_as_float(r2.y));
        acc8(acc, q3, __int_as_float(r3.y));
    }
    for (; e < end; e += 2) {
        int idx = e + half;
        int idxc = min(idx, end - 1);
        int2 r = ew[idxc];
        float w = (idx < end) ? __int_as_float(r.y) : 0.f;
        uint4 q = h[(size_t)r.x * 32 + c];
        acc8(acc, q, w);
    }

#pragma unroll
    for (int k = 0; k < 8; ++k) acc[k] += __shfl_xor(acc[k], 32, 64);

    if (half == 0) {
        float4 b0 = *(const float4*)&bias[c * 8];
        float4 b1 = *(const float4*)&bias[c * 8 + 4];
        unsigned int o0 = f2bf(fmaxf(acc[0] + b0.x, 0.f));
        unsigned int o1 = f2bf(fmaxf(acc[1] + b0.y, 0.f));
        unsigned int o2 = f2bf(fmaxf(acc[2] + b0.z, 0.f));
        unsigned int o3 = f2bf(fmaxf(acc[3] + b0.w, 0.f));
        unsigned int o4 = f2bf(fmaxf(acc[4] + b1.x, 0.f));
        unsigned int o5 = f2bf(fmaxf(acc[5] + b1.y, 0.f));
        unsigned int o6 = f2bf(fmaxf(acc[6] + b1.z, 0.f));
        unsigned int o7 = f2bf(fmaxf(acc[7] + b1.w, 0.f));
        uint4 ov;
        ov.x = o0 | (o1 << 16);
        ov.y = o2 | (o3 << 16);
        ov.z = o4 | (o5 << 16);
        ov.w = o6 | (o7 << 16);
        outb[(size_t)node * 32 + c] = ov;
    }
}

// ---------------- GEMM2: h2b[M,64] = bf16(agg1b[M,256] @ W2), MFMA ----------
__global__ __launch_bounds__(256) void gemm2_kernel(
    const unsigned short* __restrict__ Ab, const unsigned short* __restrict__ Bt,
    unsigned short* __restrict__ C, int M) {
    __shared__ unsigned short As[64][32];
    __shared__ unsigned short Bs[64][32];

    const int tid = threadIdx.x;
    const int wave = tid >> 6, lane = tid & 63;
    const int quad = lane >> 4, l15 = lane & 15;
    const int m0 = blockIdx.x * 64;

    f32x4 acc[4] = {};

    const int arow = tid >> 2;
    const int akk = (tid & 3) << 3;
    const int gr = m0 + arow;
    const int bn = tid & 63, bkc = (tid >> 6) << 3;

    for (int k0 = 0; k0 < 256; k0 += 32) {
        bf16x8 av = {};
        if (gr < M) av = *(const bf16x8*)&Ab[(size_t)gr * 256 + k0 + akk];
        *(bf16x8*)&As[arow][akk] = av;
        *(bf16x8*)&Bs[bn][bkc] = *(const bf16x8*)&Bt[(size_t)bn * 256 + k0 + bkc];
        __syncthreads();

        bf16x8 af = *(const bf16x8*)&As[wave * 16 + l15][quad * 8];
#pragma unroll
        for (int nt = 0; nt < 4; ++nt) {
            bf16x8 bfv = *(const bf16x8*)&Bs[nt * 16 + l15][quad * 8];
            acc[nt] = __builtin_amdgcn_mfma_f32_16x16x32_bf16(af, bfv, acc[nt], 0, 0, 0);
        }
        __syncthreads();
    }

#pragma unroll
    for (int nt = 0; nt < 4; ++nt) {
#pragma unroll
        for (int r = 0; r < 4; ++r) {
            int grow = m0 + wave * 16 + quad * 4 + r;
            if (grow < M) C[(size_t)grow * 64 + nt * 16 + l15] = f2bf(acc[nt][r]);
        }
    }
}

// ---- out = log_softmax(A h2b + b2), F=64 ----------------------------------
__global__ __launch_bounds__(256) void agg64_kernel(
    const uint4* __restrict__ h,  // row = 8 uint4 (64 bf16)
    const int2* __restrict__ ew, const int* __restrict__ row_ptr,
    const int* __restrict__ cnt, const float* __restrict__ bias,
    float* __restrict__ out, int N) {
    const int node = blockIdx.x * 4 + (threadIdx.x >> 6);
    if (node >= N) return;
    const int lane = threadIdx.x & 63;
    const int g = lane >> 3;
    const int c = lane & 7;

    float dv = rsqrtf((float)cnt[node] + 1.0f);
    float w0 = dv * dv;

    float acc[8] = {0.f, 0.f, 0.f, 0.f, 0.f, 0.f, 0.f, 0.f};
    {
        uint4 q = h[(size_t)node * 8 + c];
        acc8(acc, q, g == 0 ? w0 : 0.f);
    }

    const int beg = row_ptr[node], end = row_ptr[node + 1];
    int e = beg;
    for (; e + 16 <= end; e += 16) {
        int2 r0 = ew[e + g];
        int2 r1 = ew[e + 8 + g];
        uint4 q0 = h[(size_t)r0.x * 8 + c];
        uint4 q1 = h[(size_t)r1.x * 8 + c];
        acc8(acc, q0, __int_as_float(r0.y));
        acc8(acc, q1, __int_as_float(r1.y));
    }
    for (; e < end; e += 8) {
        int idx = e + g;
        int idxc = min(idx, end - 1);
        int2 r = ew[idxc];
        float w = (idx < end) ? __int_as_float(r.y) : 0.f;
        uint4 q = h[(size_t)r.x * 8 + c];
        acc8(acc, q, w);
    }

#pragma unroll
    for (int k = 0; k < 8; ++k) {
        acc[k] += __shfl_xor(acc[k], 8, 64);
        acc[k] += __shfl_xor(acc[k], 16, 64);
        acc[k] += __shfl_xor(acc[k], 32, 64);
    }

    float4 b0 = *(const float4*)&bias[c * 8];
    float4 b1 = *(const float4*)&bias[c * 8 + 4];
    float v[8];
    v[0] = acc[0] + b0.x; v[1] = acc[1] + b0.y;
    v[2] = acc[2] + b0.z; v[3] = acc[3] + b0.w;
    v[4] = acc[4] + b1.x; v[5] = acc[5] + b1.y;
    v[6] = acc[6] + b1.z; v[7] = acc[7] + b1.w;

    float m = v[0];
#pragma unroll
    for (int k = 1; k < 8; ++k) m = fmaxf(m, v[k]);
    m = fmaxf(m, __shfl_xor(m, 1, 64));
    m = fmaxf(m, __shfl_xor(m, 2, 64));
    m = fmaxf(m, __shfl_xor(m, 4, 64));
    float s = 0.f;
#pragma unroll
    for (int k = 0; k < 8; ++k) s += expf(v[k] - m);
    s += __shfl_xor(s, 1, 64);
    s += __shfl_xor(s, 2, 64);
    s += __shfl_xor(s, 4, 64);
    float ls = m + logf(s);

    if (g == 0) {
        float4 o0, o1;
        o0.x = v[0] - ls; o0.y = v[1] - ls; o0.z = v[2] - ls; o0.w = v[3] - ls;
        o1.x = v[4] - ls; o1.y = v[5] - ls; o1.z = v[6] - ls; o1.w = v[7] - ls;
        *(float4*)&out[(size_t)node * 64 + c * 8] = o0;
        *(float4*)&out[(size_t)node * 64 + c * 8 + 4] = o1;
    }
}

extern "C" void kernel_launch(void* const* d_in, const int* in_sizes, int n_in,
                              void* d_out, int out_size, void* d_ws, size_t ws_size,
                              hipStream_t stream) {
    const float* x  = (const float*)d_in[0];
    const int*   ei = (const int*)d_in[1];
    const float* W1 = (const float*)d_in[2];
    const float* b1 = (const float*)d_in[3];
    const float* W2 = (const float*)d_in[4];
    const float* b2 = (const float*)d_in[5];
    float* out = (float*)d_out;

    const int N = in_sizes[0] / 256;  // 100000
    const int E = in_sizes[1] / 2;    // 1600000
    const int NP = 102400;
    const int NB = (N + 1023) / 1024;  // scan blocks (98)

    // Workspace layout (bytes; 16B-aligned segments). Total ~130 MB.
    char* ws = (char*)d_ws;
    int*   cnt     = (int*)ws;                 ws += (size_t)NP * 4;
    int*   rank    = (int*)ws;                 ws += (size_t)E * 4;
    int*   row_ptr = (int*)ws;                 ws += (size_t)(NP + 4) * 4;
    int*   bsum    = (int*)ws;                 ws += (size_t)1024 * 4;
    int*   boffs   = (int*)ws;                 ws += (size_t)1024 * 4;
    int2*  csr_ew  = (int2*)ws;                ws += (size_t)E * 8;
    unsigned short* W1t   = (unsigned short*)ws; ws += (size_t)256 * 256 * 2;
    unsigned short* W2t   = (unsigned short*)ws; ws += (size_t)256 * 64 * 2;
    unsigned short* h1b   = (unsigned short*)ws; ws += (size_t)N * 256 * 2;
    unsigned short* agg1b = (unsigned short*)ws; ws += (size_t)N * 256 * 2;
    unsigned short* h2b   = (unsigned short*)ws; ws += (size_t)N * 64 * 2;

    hipMemsetAsync(cnt, 0, (size_t)N * sizeof(int), stream);

    // CSR build (one atomic pass; scatter is atomic-free)
    deg_rank_kernel<<<(E + 255) / 256, 256, 0, stream>>>(ei + E, E, cnt, rank);
    scan_part1_kernel<<<NB, 256, 0, stream>>>(cnt, bsum, N);
    scan_part2_kernel<<<1, 1024, 0, stream>>>(bsum, boffs, NB, row_ptr, N);
    scan_part3_kernel<<<NB, 256, 0, stream>>>(cnt, boffs, row_ptr, N);
    scatter_kernel<<<(E + 255) / 256, 256, 0, stream>>>(
        ei, ei + E, rank, cnt, row_ptr, csr_ew, E);

    // weight casts (merged)
    castw_kernel<<<(65536 + 16384 + 255) / 256, 256, 0, stream>>>(W1, W2, W1t, W2t);

    // h1b = bf16(x @ W1)
    gemm1_kernel<<<(N + 127) / 128, 256, 0, stream>>>(x, W1t, h1b, N);

    // agg1b = bf16(relu(A h1b + b1))
    agg256b_kernel<<<(N + 3) / 4, 256, 0, stream>>>(
        (const uint4*)h1b, csr_ew, row_ptr, cnt, b1, (uint4*)agg1b, N);

    // h2b = bf16(agg1b @ W2)
    gemm2_kernel<<<(N + 63) / 64, 256, 0, stream>>>(agg1b, W2t, h2b, N);

    // out = log_softmax(A h2b + b2)
    agg64_kernel<<<(N + 3) / 4, 256, 0, stream>>>(
        (const uint4*)h2b, csr_ew, row_ptr, cnt, b2, out, N);
}

// Round 8
// 543.473 us; speedup vs baseline: 4.6781x; 1.0200x over previous
//
#include <hip/hip_runtime.h>
#include <math.h>

// ---------------------------------------------------------------------------
// GCN 2-layer forward on MI355X. Round 8: fuse gemm2 into agg256.
//   aggfused: block = 16 nodes (4 waves x 4 nodes). Gather phase identical to
//   agg256b; relu(agg1+b1) rows land in a 16x256 LDS tile (bf16, +16B pad);
//   one barrier; 16x64x256 MFMA epilog (8 mfma/wave, B-frags from L2-hot W2t)
//   writes h2b directly. agg1b buffer and gemm2 dispatch are gone.
//   Everything else unchanged from round 7.
// ---------------------------------------------------------------------------

typedef __attribute__((ext_vector_type(8))) short bf16x8;
typedef __attribute__((ext_vector_type(4))) float f32x4;

__device__ inline unsigned short f2bf(float f) {
    union { float f; unsigned int u; } v; v.f = f;
    unsigned int r = v.u + 0x7fffu + ((v.u >> 16) & 1u);  // RNE
    return (unsigned short)(r >> 16);
}
__device__ inline float bf2f_lo(unsigned int u) {
    union { unsigned int u; float f; } v; v.u = u << 16; return v.f;
}
__device__ inline float bf2f_hi(unsigned int u) {
    union { unsigned int u; float f; } v; v.u = u & 0xffff0000u; return v.f;
}

// unpack uint4 (8 bf16) and FMA into acc[8] with weight w
__device__ inline void acc8(float* acc, uint4 q, float w) {
    acc[0] += bf2f_lo(q.x) * w; acc[1] += bf2f_hi(q.x) * w;
    acc[2] += bf2f_lo(q.y) * w; acc[3] += bf2f_hi(q.y) * w;
    acc[4] += bf2f_lo(q.z) * w; acc[5] += bf2f_hi(q.z) * w;
    acc[6] += bf2f_lo(q.w) * w; acc[7] += bf2f_hi(q.w) * w;
}

// ---------------- CSR build ----------------
__global__ __launch_bounds__(256) void deg_rank_kernel(
    const int* __restrict__ dst, int E, int* __restrict__ cnt,
    int* __restrict__ rank) {
    int e = blockIdx.x * blockDim.x + threadIdx.x;
    if (e < E) rank[e] = atomicAdd(&cnt[dst[e]], 1);
}

__global__ __launch_bounds__(256) void scan_part1_kernel(
    const int* __restrict__ cnt, int* __restrict__ bsum, int N) {
    __shared__ int s[256];
    const int tid = threadIdx.x;
    int base = blockIdx.x * 1024 + tid * 4;
    int v = 0;
#pragma unroll
    for (int j = 0; j < 4; ++j)
        if (base + j < N) v += cnt[base + j];
    s[tid] = v;
    __syncthreads();
    for (int off = 128; off > 0; off >>= 1) {
        if (tid < off) s[tid] += s[tid + off];
        __syncthreads();
    }
    if (tid == 0) bsum[blockIdx.x] = s[0];
}

__global__ __launch_bounds__(1024) void scan_part2_kernel(
    const int* __restrict__ bsum, int* __restrict__ boffs, int NB,
    int* __restrict__ row_ptr, int N) {
    __shared__ int s[1024];
    const int tid = threadIdx.x;
    int v = (tid < NB) ? bsum[tid] : 0;
    s[tid] = v;
    __syncthreads();
    for (int off = 1; off < 1024; off <<= 1) {
        int t = (tid >= off) ? s[tid - off] : 0;
        __syncthreads();
        if (tid >= off) s[tid] += t;
        __syncthreads();
    }
    if (tid < NB) boffs[tid] = s[tid] - v;  // exclusive
    if (tid == 1023) row_ptr[N] = s[1023];  // grand total
}

__global__ __launch_bounds__(256) void scan_part3_kernel(
    const int* __restrict__ cnt, const int* __restrict__ boffs,
    int* __restrict__ row_ptr, int N) {
    __shared__ int s[256];
    const int tid = threadIdx.x;
    int base = blockIdx.x * 1024 + tid * 4;
    int c[4];
    int v = 0;
#pragma unroll
    for (int j = 0; j < 4; ++j) {
        c[j] = (base + j < N) ? cnt[base + j] : 0;
        v += c[j];
    }
    s[tid] = v;
    __syncthreads();
    for (int off = 1; off < 256; off <<= 1) {
        int t = (tid >= off) ? s[tid - off] : 0;
        __syncthreads();
        if (tid >= off) s[tid] += t;
        __syncthreads();
    }
    int run = boffs[blockIdx.x] + s[tid] - v;
#pragma unroll
    for (int j = 0; j < 4; ++j) {
        if (base + j < N) {
            row_ptr[base + j] = run;
            run += c[j];
        }
    }
}

// Atomic-free scatter: slot = row_ptr[dst] + rank.
__global__ __launch_bounds__(256) void scatter_kernel(
    const int* __restrict__ src, const int* __restrict__ dst,
    const int* __restrict__ rank, const int* __restrict__ cnt,
    const int* __restrict__ row_ptr, int2* __restrict__ csr_ew, int E) {
    int e = blockIdx.x * blockDim.x + threadIdx.x;
    if (e >= E) return;
    int s = src[e], d = dst[e];
    float w = rsqrtf((float)cnt[s] + 1.0f) * rsqrtf((float)cnt[d] + 1.0f);
    int pos = row_ptr[d] + rank[e];
    int2 rec;
    rec.x = s;
    rec.y = __float_as_int(w);
    csr_ew[pos] = rec;
}

// ------ merged weight cast+transpose: W1t[n][k], W2t[n][k] (bf16) ----------
__global__ __launch_bounds__(256) void castw_kernel(
    const float* __restrict__ W1, const float* __restrict__ W2,
    unsigned short* __restrict__ W1t, unsigned short* __restrict__ W2t) {
    int i = blockIdx.x * 256 + threadIdx.x;
    if (i < 65536) {  // W1: 256x256
        int n = i >> 8, k = i & 255;
        W1t[i] = f2bf(W1[(size_t)k * 256 + n]);
    } else if (i < 65536 + 16384) {  // W2: 256x64 -> W2t[64][256]
        int j = i - 65536;
        int n = j >> 8, k = j & 255;
        W2t[j] = f2bf(W2[(size_t)k * 64 + n]);
    }
}

// ---------------- GEMM1: h1b[M,256] = bf16(x[M,256] @ W1), MFMA -------------
// 128(M) x 256(N) tile, BK=32. Wave w owns cols [64w, 64w+64). 32 MFMA/iter/wave.
__global__ __launch_bounds__(256) void gemm1_kernel(
    const float* __restrict__ A, const unsigned short* __restrict__ Bt,
    unsigned short* __restrict__ C, int M) {
    __shared__ unsigned short As[128][32];   // 8 KB
    __shared__ unsigned short Bs[256][32];   // 16 KB

    const int tid = threadIdx.x;
    const int wave = tid >> 6, lane = tid & 63;
    const int quad = lane >> 4, l15 = lane & 15;
    const int m0 = blockIdx.x * 128;

    f32x4 acc[8][4] = {};

    const int arow = tid >> 1;          // 0..127
    const int akk  = (tid & 1) << 4;    // 0 or 16
    const int gr = m0 + arow;

    for (int k0 = 0; k0 < 256; k0 += 32) {
        float4 a0 = make_float4(0.f,0.f,0.f,0.f), a1 = a0, a2 = a0, a3 = a0;
        if (gr < M) {
            const float* ap = &A[(size_t)gr * 256 + k0 + akk];
            a0 = *(const float4*)&ap[0];
            a1 = *(const float4*)&ap[4];
            a2 = *(const float4*)&ap[8];
            a3 = *(const float4*)&ap[12];
        }
        bf16x8 av0, av1;
        av0[0] = (short)f2bf(a0.x); av0[1] = (short)f2bf(a0.y);
        av0[2] = (short)f2bf(a0.z); av0[3] = (short)f2bf(a0.w);
        av0[4] = (short)f2bf(a1.x); av0[5] = (short)f2bf(a1.y);
        av0[6] = (short)f2bf(a1.z); av0[7] = (short)f2bf(a1.w);
        av1[0] = (short)f2bf(a2.x); av1[1] = (short)f2bf(a2.y);
        av1[2] = (short)f2bf(a2.z); av1[3] = (short)f2bf(a2.w);
        av1[4] = (short)f2bf(a3.x); av1[5] = (short)f2bf(a3.y);
        av1[6] = (short)f2bf(a3.z); av1[7] = (short)f2bf(a3.w);
        *(bf16x8*)&As[arow][akk]     = av0;
        *(bf16x8*)&As[arow][akk + 8] = av1;

        const unsigned short* bsrc = &Bt[(size_t)tid * 256 + k0];
        *(bf16x8*)&Bs[tid][0]  = *(const bf16x8*)&bsrc[0];
        *(bf16x8*)&Bs[tid][8]  = *(const bf16x8*)&bsrc[8];
        *(bf16x8*)&Bs[tid][16] = *(const bf16x8*)&bsrc[16];
        *(bf16x8*)&Bs[tid][24] = *(const bf16x8*)&bsrc[24];
        __syncthreads();

        bf16x8 bfv[4];
#pragma unroll
        for (int nt = 0; nt < 4; ++nt)
            bfv[nt] = *(const bf16x8*)&Bs[wave * 64 + nt * 16 + l15][quad * 8];
#pragma unroll
        for (int mt = 0; mt < 8; ++mt) {
            bf16x8 af = *(const bf16x8*)&As[mt * 16 + l15][quad * 8];
#pragma unroll
            for (int nt = 0; nt < 4; ++nt)
                acc[mt][nt] = __builtin_amdgcn_mfma_f32_16x16x32_bf16(
                    af, bfv[nt], acc[mt][nt], 0, 0, 0);
        }
        __syncthreads();
    }

#pragma unroll
    for (int mt = 0; mt < 8; ++mt) {
#pragma unroll
        for (int nt = 0; nt < 4; ++nt) {
            int gcol = wave * 64 + nt * 16 + l15;
#pragma unroll
            for (int r = 0; r < 4; ++r) {
                int grow = m0 + mt * 16 + quad * 4 + r;
                if (grow < M)
                    C[(size_t)grow * 256 + gcol] = f2bf(acc[mt][nt][r]);
            }
        }
    }
}

// ---- FUSED: h2b = bf16( relu(A h1b + b1) @ W2 ), 16 nodes per block -------
// Phase 1 (per wave, 4 nodes): gather exactly like agg256b, deposit bf16
// relu rows into LDS tile As[16][256+8]. Phase 2: 16x64x256 MFMA epilog.
__global__ __launch_bounds__(256) void aggfused_kernel(
    const uint4* __restrict__ h,  // h1b rows = 32 uint4 (256 bf16)
    const int2* __restrict__ ew,
    const int* __restrict__ row_ptr, const int* __restrict__ cnt,
    const float* __restrict__ bias, const unsigned short* __restrict__ W2t,
    unsigned short* __restrict__ h2b, int N) {
    __shared__ unsigned short As[16][264];  // +8 bf16 pad: 2-way-free LDS reads

    const int tid = threadIdx.x;
    const int wave = tid >> 6, lane = tid & 63;
    const int half = lane >> 5;
    const int c = lane & 31;
    const int node0 = blockIdx.x * 16;

    for (int i = 0; i < 4; ++i) {
        const int local = wave * 4 + i;
        const int node = node0 + local;
        float acc[8] = {0.f, 0.f, 0.f, 0.f, 0.f, 0.f, 0.f, 0.f};
        if (node < N) {
            float dv = rsqrtf((float)cnt[node] + 1.0f);
            float w0 = dv * dv;
            {
                uint4 q = h[(size_t)node * 32 + c];
                acc8(acc, q, half == 0 ? w0 : 0.f);
            }
            const int beg = row_ptr[node], end = row_ptr[node + 1];
            int e = beg;
            for (; e + 8 <= end; e += 8) {
                int2 r0 = ew[e + 0 + half];
                int2 r1 = ew[e + 2 + half];
                int2 r2 = ew[e + 4 + half];
                int2 r3 = ew[e + 6 + half];
                uint4 q0 = h[(size_t)r0.x * 32 + c];
                uint4 q1 = h[(size_t)r1.x * 32 + c];
                uint4 q2 = h[(size_t)r2.x * 32 + c];
                uint4 q3 = h[(size_t)r3.x * 32 + c];
                acc8(acc, q0, __int_as_float(r0.y));
                acc8(acc, q1, __int_as_float(r1.y));
                acc8(acc, q2, __int_as_float(r2.y));
                acc8(acc, q3, __int_as_float(r3.y));
            }
            for (; e < end; e += 2) {
                int idx = e + half;
                int idxc = min(idx, end - 1);
                int2 r = ew[idxc];
                float w = (idx < end) ? __int_as_float(r.y) : 0.f;
                uint4 q = h[(size_t)r.x * 32 + c];
                acc8(acc, q, w);
            }
        }
#pragma unroll
        for (int k = 0; k < 8; ++k) acc[k] += __shfl_xor(acc[k], 32, 64);

        if (half == 0) {
            float4 b0 = *(const float4*)&bias[c * 8];
            float4 b1 = *(const float4*)&bias[c * 8 + 4];
            unsigned int o0 = f2bf(fmaxf(acc[0] + b0.x, 0.f));
            unsigned int o1 = f2bf(fmaxf(acc[1] + b0.y, 0.f));
            unsigned int o2 = f2bf(fmaxf(acc[2] + b0.z, 0.f));
            unsigned int o3 = f2bf(fmaxf(acc[3] + b0.w, 0.f));
            unsigned int o4 = f2bf(fmaxf(acc[4] + b1.x, 0.f));
            unsigned int o5 = f2bf(fmaxf(acc[5] + b1.y, 0.f));
            unsigned int o6 = f2bf(fmaxf(acc[6] + b1.z, 0.f));
            unsigned int o7 = f2bf(fmaxf(acc[7] + b1.w, 0.f));
            uint4 ov;
            ov.x = o0 | (o1 << 16);
            ov.y = o2 | (o3 << 16);
            ov.z = o4 | (o5 << 16);
            ov.w = o6 | (o7 << 16);
            *(uint4*)&As[local][c * 8] = ov;
        }
    }
    __syncthreads();

    // Phase 2: D[16 nodes][64 cols] = As[16][256] @ W2t^T. Wave w: cols
    // [16w, 16w+16). 8 MFMAs. B-frags straight from global (L2-hot, 32 KB).
    const int quad = lane >> 4, l15 = lane & 15;
    f32x4 accd = {};
#pragma unroll
    for (int k0 = 0; k0 < 8; ++k0) {
        bf16x8 af = *(const bf16x8*)&As[l15][k0 * 32 + quad * 8];
        bf16x8 bf = *(const bf16x8*)&W2t[(size_t)(wave * 16 + l15) * 256 +
                                         k0 * 32 + quad * 8];
        accd = __builtin_amdgcn_mfma_f32_16x16x32_bf16(af, bf, accd, 0, 0, 0);
    }
#pragma unroll
    for (int r = 0; r < 4; ++r) {
        int node = node0 + quad * 4 + r;
        if (node < N)
            h2b[(size_t)node * 64 + wave * 16 + l15] = f2bf(accd[r]);
    }
}

// ---- out = log_softmax(A h2b + b2), F=64 ----------------------------------
__global__ __launch_bounds__(256) void agg64_kernel(
    const uint4* __restrict__ h,  // row = 8 uint4 (64 bf16)
    const int2* __restrict__ ew, const int* __restrict__ row_ptr,
    const int* __restrict__ cnt, const float* __restrict__ bias,
    float* __restrict__ out, int N) {
    const int node = blockIdx.x * 4 + (threadIdx.x >> 6);
    if (node >= N) return;
    const int lane = threadIdx.x & 63;
    const int g = lane >> 3;
    const int c = lane & 7;

    float dv = rsqrtf((float)cnt[node] + 1.0f);
    float w0 = dv * dv;

    float acc[8] = {0.f, 0.f, 0.f, 0.f, 0.f, 0.f, 0.f, 0.f};
    {
        uint4 q = h[(size_t)node * 8 + c];
        acc8(acc, q, g == 0 ? w0 : 0.f);
    }

    const int beg = row_ptr[node], end = row_ptr[node + 1];
    int e = beg;
    for (; e + 16 <= end; e += 16) {
        int2 r0 = ew[e + g];
        int2 r1 = ew[e + 8 + g];
        uint4 q0 = h[(size_t)r0.x * 8 + c];
        uint4 q1 = h[(size_t)r1.x * 8 + c];
        acc8(acc, q0, __int_as_float(r0.y));
        acc8(acc, q1, __int_as_float(r1.y));
    }
    for (; e < end; e += 8) {
        int idx = e + g;
        int idxc = min(idx, end - 1);
        int2 r = ew[idxc];
        float w = (idx < end) ? __int_as_float(r.y) : 0.f;
        uint4 q = h[(size_t)r.x * 8 + c];
        acc8(acc, q, w);
    }

#pragma unroll
    for (int k = 0; k < 8; ++k) {
        acc[k] += __shfl_xor(acc[k], 8, 64);
        acc[k] += __shfl_xor(acc[k], 16, 64);
        acc[k] += __shfl_xor(acc[k], 32, 64);
    }

    float4 b0 = *(const float4*)&bias[c * 8];
    float4 b1 = *(const float4*)&bias[c * 8 + 4];
    float v[8];
    v[0] = acc[0] + b0.x; v[1] = acc[1] + b0.y;
    v[2] = acc[2] + b0.z; v[3] = acc[3] + b0.w;
    v[4] = acc[4] + b1.x; v[5] = acc[5] + b1.y;
    v[6] = acc[6] + b1.z; v[7] = acc[7] + b1.w;

    float m = v[0];
#pragma unroll
    for (int k = 1; k < 8; ++k) m = fmaxf(m, v[k]);
    m = fmaxf(m, __shfl_xor(m, 1, 64));
    m = fmaxf(m, __shfl_xor(m, 2, 64));
    m = fmaxf(m, __shfl_xor(m, 4, 64));
    float s = 0.f;
#pragma unroll
    for (int k = 0; k < 8; ++k) s += expf(v[k] - m);
    s += __shfl_xor(s, 1, 64);
    s += __shfl_xor(s, 2, 64);
    s += __shfl_xor(s, 4, 64);
    float ls = m + logf(s);

    if (g == 0) {
        float4 o0, o1;
        o0.x = v[0] - ls; o0.y = v[1] - ls; o0.z = v[2] - ls; o0.w = v[3] - ls;
        o1.x = v[4] - ls; o1.y = v[5] - ls; o1.z = v[6] - ls; o1.w = v[7] - ls;
        *(float4*)&out[(size_t)node * 64 + c * 8] = o0;
        *(float4*)&out[(size_t)node * 64 + c * 8 + 4] = o1;
    }
}

extern "C" void kernel_launch(void* const* d_in, const int* in_sizes, int n_in,
                              void* d_out, int out_size, void* d_ws, size_t ws_size,
                              hipStream_t stream) {
    const float* x  = (const float*)d_in[0];
    const int*   ei = (const int*)d_in[1];
    const float* W1 = (const float*)d_in[2];
    const float* b1 = (const float*)d_in[3];
    const float* W2 = (const float*)d_in[4];
    const float* b2 = (const float*)d_in[5];
    float* out = (float*)d_out;

    const int N = in_sizes[0] / 256;  // 100000
    const int E = in_sizes[1] / 2;    // 1600000
    const int NP = 102400;
    const int NB = (N + 1023) / 1024;  // scan blocks (98)

    // Workspace layout (bytes; 16B-aligned segments). Total ~90 MB.
    char* ws = (char*)d_ws;
    int*   cnt     = (int*)ws;                 ws += (size_t)NP * 4;
    int*   rank    = (int*)ws;                 ws += (size_t)E * 4;
    int*   row_ptr = (int*)ws;                 ws += (size_t)(NP + 4) * 4;
    int*   bsum    = (int*)ws;                 ws += (size_t)1024 * 4;
    int*   boffs   = (int*)ws;                 ws += (size_t)1024 * 4;
    int2*  csr_ew  = (int2*)ws;                ws += (size_t)E * 8;
    unsigned short* W1t   = (unsigned short*)ws; ws += (size_t)256 * 256 * 2;
    unsigned short* W2t   = (unsigned short*)ws; ws += (size_t)256 * 64 * 2;
    unsigned short* h1b   = (unsigned short*)ws; ws += (size_t)N * 256 * 2;
    unsigned short* h2b   = (unsigned short*)ws; ws += (size_t)N * 64 * 2;

    hipMemsetAsync(cnt, 0, (size_t)N * sizeof(int), stream);

    // CSR build (one atomic pass; scatter is atomic-free)
    deg_rank_kernel<<<(E + 255) / 256, 256, 0, stream>>>(ei + E, E, cnt, rank);
    scan_part1_kernel<<<NB, 256, 0, stream>>>(cnt, bsum, N);
    scan_part2_kernel<<<1, 1024, 0, stream>>>(bsum, boffs, NB, row_ptr, N);
    scan_part3_kernel<<<NB, 256, 0, stream>>>(cnt, boffs, row_ptr, N);
    scatter_kernel<<<(E + 255) / 256, 256, 0, stream>>>(
        ei, ei + E, rank, cnt, row_ptr, csr_ew, E);

    // weight casts (merged)
    castw_kernel<<<(65536 + 16384 + 255) / 256, 256, 0, stream>>>(W1, W2, W1t, W2t);

    // h1b = bf16(x @ W1)
    gemm1_kernel<<<(N + 127) / 128, 256, 0, stream>>>(x, W1t, h1b, N);

    // h2b = bf16( relu(A h1b + b1) @ W2 )  [fused aggregation + GEMM2]
    aggfused_kernel<<<(N + 15) / 16, 256, 0, stream>>>(
        (const uint4*)h1b, csr_ew, row_ptr, cnt, b1, W2t, h2b, N);

    // out = log_softmax(A h2b + b2)
    agg64_kernel<<<(N + 3) / 4, 256, 0, stream>>>(
        (const uint4*)h2b, csr_ew, row_ptr, cnt, b2, out, N);
}